// Round 1
// baseline (793.273 us; speedup 1.0000x reference)
//
#include <hip/hip_runtime.h>
#include <math.h>

#define NN 100000      // nodes
#define NE 1600000     // edges
#define DH 128         // feature dim
#define NG 512         // graphs
#define NC 10          // classes
#define NB_SCAN 98     // ceil(NN/1024)

// ---------------- CSR build ----------------

__global__ void k_zero(int* __restrict__ counts, float* __restrict__ pooled) {
    int i = blockIdx.x * 256 + threadIdx.x;
    if (i < NN) counts[i] = 0;
    if (i < NG * DH) pooled[i] = 0.f;
}

__global__ void k_hist(const int* __restrict__ dst, int* __restrict__ counts) {
    int e = blockIdx.x * 256 + threadIdx.x;
    if (e < NE) atomicAdd(&counts[dst[e]], 1);
}

// each block scans 1024 counts (256 thr x 4), writes exclusive offsets + block sum
__global__ void k_scan_blocks(const int* __restrict__ counts, int* __restrict__ offsets,
                              int* __restrict__ bsum) {
    __shared__ int sd[256];
    int t = threadIdx.x;
    int base = blockIdx.x * 1024 + t * 4;
    int v0 = (base + 0 < NN) ? counts[base + 0] : 0;
    int v1 = (base + 1 < NN) ? counts[base + 1] : 0;
    int v2 = (base + 2 < NN) ? counts[base + 2] : 0;
    int v3 = (base + 3 < NN) ? counts[base + 3] : 0;
    int s = v0 + v1 + v2 + v3;
    sd[t] = s;
    __syncthreads();
    for (int off = 1; off < 256; off <<= 1) {
        int x = (t >= off) ? sd[t - off] : 0;
        __syncthreads();
        sd[t] += x;
        __syncthreads();
    }
    int run = sd[t] - s;   // exclusive prefix of this thread's 4 elems
    if (base + 0 < NN) offsets[base + 0] = run; run += v0;
    if (base + 1 < NN) offsets[base + 1] = run; run += v1;
    if (base + 2 < NN) offsets[base + 2] = run; run += v2;
    if (base + 3 < NN) offsets[base + 3] = run; run += v3;
    if (t == 255) bsum[blockIdx.x] = run;  // block total
}

__global__ void k_scan_bsum(int* __restrict__ bsum) {
    __shared__ int sd[128];
    int t = threadIdx.x;
    int v = (t < NB_SCAN) ? bsum[t] : 0;
    sd[t] = v;
    __syncthreads();
    for (int off = 1; off < 128; off <<= 1) {
        int x = (t >= off) ? sd[t - off] : 0;
        __syncthreads();
        sd[t] += x;
        __syncthreads();
    }
    if (t < NB_SCAN) bsum[t] = sd[t] - v;  // exclusive
}

__global__ void k_add_base(int* __restrict__ offsets, const int* __restrict__ bsum,
                           int* __restrict__ cursor) {
    int i = blockIdx.x * 256 + threadIdx.x;
    if (i < NN) {
        int o = offsets[i] + bsum[i >> 10];
        offsets[i] = o;
        cursor[i] = o;
    }
    if (i == 0) offsets[NN] = NE;
}

__global__ void k_fill(const int* __restrict__ src, const int* __restrict__ dst,
                       int* __restrict__ cursor, int* __restrict__ csr) {
    int e = blockIdx.x * 256 + threadIdx.x;
    if (e < NE) {
        int d = dst[e];
        int p = atomicAdd(&cursor[d], 1);
        csr[p] = src[e];
    }
}

// ---------------- fused aggregate + matvec (+ optional pooling) ----------------
// 16 nodes per block, 256 threads. W cached in LDS (64KB), agg rows in LDS (8KB).
// Gather: 32 lanes/node, float4/lane (16B), edges unrolled x4 with unconditional
// clamped loads + predicated adds to keep row loads in flight.
// Matvec: thread = channel c (128) x half (2); 8 nodes/thread amortize each W read.

template <int RELU, int POOL>
__global__ __launch_bounds__(256, 2) void k_agg_mm(
    const float* __restrict__ in, const float* __restrict__ W,
    const float* __restrict__ bias, const int* __restrict__ offs,
    const int* __restrict__ csr, const int* __restrict__ gidx,
    float* __restrict__ out, float* __restrict__ pooled) {
    __shared__ __align__(16) float sW[DH * DH];
    __shared__ __align__(16) float sA[16][DH];
    int t = threadIdx.x;
    {
        const float4* W4 = (const float4*)W;
        float4* sW4 = (float4*)sW;
        for (int i = t; i < DH * DH / 4; i += 256) sW4[i] = W4[i];
    }
    int node0 = blockIdx.x * 16;
    int which = t >> 7;          // 0/1
    int lane = t & 31;           // float4 lane within row
    int sub = (t >> 5) & 3;      // node within quad
    const float4* in4 = (const float4*)in;

    for (int it = 0; it < 2; ++it) {
        int p = which * 8 + it * 4 + sub;   // covers 0..15 exactly once
        int node = node0 + p;
        float4 a = in4[node * 32 + lane];   // self loop
        int e0 = offs[node], e1 = offs[node + 1];
        for (int e = e0; e < e1; e += 4) {
            int i1 = (e + 1 < NE) ? e + 1 : NE - 1;
            int i2 = (e + 2 < NE) ? e + 2 : NE - 1;
            int i3 = (e + 3 < NE) ? e + 3 : NE - 1;
            int s0 = csr[e], s1 = csr[i1], s2 = csr[i2], s3 = csr[i3];
            bool m1 = (e + 1 < e1), m2 = (e + 2 < e1), m3 = (e + 3 < e1);
            float4 v0 = in4[s0 * 32 + lane];
            float4 v1 = in4[s1 * 32 + lane];
            float4 v2 = in4[s2 * 32 + lane];
            float4 v3 = in4[s3 * 32 + lane];
            a.x += v0.x; a.y += v0.y; a.z += v0.z; a.w += v0.w;
            a.x += m1 ? v1.x : 0.f; a.y += m1 ? v1.y : 0.f;
            a.z += m1 ? v1.z : 0.f; a.w += m1 ? v1.w : 0.f;
            a.x += m2 ? v2.x : 0.f; a.y += m2 ? v2.y : 0.f;
            a.z += m2 ? v2.z : 0.f; a.w += m2 ? v2.w : 0.f;
            a.x += m3 ? v3.x : 0.f; a.y += m3 ? v3.y : 0.f;
            a.z += m3 ? v3.z : 0.f; a.w += m3 ? v3.w : 0.f;
        }
        ((float4*)&sA[p][0])[lane] = a;
    }
    __syncthreads();

    int c = t & 127;
    float bv = bias[c];
    float acc[8];
#pragma unroll
    for (int j = 0; j < 8; ++j) acc[j] = bv;
#pragma unroll 4
    for (int k = 0; k < DH; ++k) {
        float w = sW[k * DH + c];
#pragma unroll
        for (int j = 0; j < 8; ++j) acc[j] = fmaf(sA[which + 2 * j][k], w, acc[j]);
    }

    if (POOL) {
        __syncthreads();
#pragma unroll
        for (int j = 0; j < 8; ++j) sA[which + 2 * j][c] = acc[j];
        __syncthreads();
        if (which == 0) {   // 128 threads: run-length reduce over sorted gidx
            int gprev = gidx[node0];
            float run = 0.f;
            for (int p = 0; p < 16; ++p) {
                int g = gidx[node0 + p];
                if (g != gprev) {
                    atomicAdd(&pooled[gprev * DH + c], run);
                    run = 0.f;
                    gprev = g;
                }
                run += sA[p][c];
            }
            atomicAdd(&pooled[gprev * DH + c], run);
        }
    } else {
#pragma unroll
        for (int j = 0; j < 8; ++j) {
            float v = acc[j];
            if (RELU) v = fmaxf(v, 0.f);
            out[(node0 + which + 2 * j) * DH + c] = v;
        }
    }
}

// ---------------- batchnorm stats ----------------

__global__ void k_bnstats(const float* __restrict__ pooled, float* __restrict__ mean,
                          float* __restrict__ rstd) {
    int c = blockIdx.x;    // 128 blocks, one per channel
    int l = threadIdx.x;   // 64 threads
    float s = 0.f, s2 = 0.f;
    for (int g = l; g < NG; g += 64) {
        float v = pooled[g * DH + c];
        s += v;
        s2 += v * v;
    }
#pragma unroll
    for (int off = 32; off > 0; off >>= 1) {
        s += __shfl_down(s, off, 64);
        s2 += __shfl_down(s2, off, 64);
    }
    if (l == 0) {
        float m = s * (1.f / NG);
        float var = s2 * (1.f / NG) - m * m;
        mean[c] = m;
        rstd[c] = rsqrtf(var + 1e-5f);
    }
}

// ---------------- BN + W3 + relu + W4 + log_softmax ----------------

__global__ __launch_bounds__(128) void k_tail(
    const float* __restrict__ pooled, const float* __restrict__ mean,
    const float* __restrict__ rstd, const float* __restrict__ gamma,
    const float* __restrict__ beta, const float* __restrict__ W3,
    const float* __restrict__ b3, const float* __restrict__ W4,
    const float* __restrict__ b4, float* __restrict__ out) {
    __shared__ __align__(16) float sW[DH * DH];
    __shared__ float sg[DH];
    __shared__ float sz[DH];
    __shared__ float slog[NC];
    __shared__ float slse;
    int g = blockIdx.x, t = threadIdx.x;
    {
        const float4* W34 = (const float4*)W3;
        float4* sW4 = (float4*)sW;
        for (int i = t; i < DH * DH / 4; i += 128) sW4[i] = W34[i];
    }
    float v = pooled[g * DH + t];
    v = (v - mean[t]) * rstd[t] * gamma[t] + beta[t];
    sg[t] = v;
    __syncthreads();
    float acc = b3[t];
#pragma unroll 4
    for (int k = 0; k < DH; ++k) acc = fmaf(sg[k], sW[k * DH + t], acc);
    sz[t] = fmaxf(acc, 0.f);
    __syncthreads();
    if (t < NC) {
        float a = b4[t];
        for (int k = 0; k < DH; ++k) a = fmaf(sz[k], W4[k * NC + t], a);
        slog[t] = a;
    }
    __syncthreads();
    if (t == 0) {
        float mx = slog[0];
        for (int j = 1; j < NC; ++j) mx = fmaxf(mx, slog[j]);
        float se = 0.f;
        for (int j = 0; j < NC; ++j) se += expf(slog[j] - mx);
        slse = mx + logf(se);
    }
    __syncthreads();
    if (t < NC) out[g * NC + t] = slog[t] - slse;
}

// ---------------- launch ----------------

extern "C" void kernel_launch(void* const* d_in, const int* in_sizes, int n_in,
                              void* d_out, int out_size, void* d_ws, size_t ws_size,
                              hipStream_t stream) {
    const float* x = (const float*)d_in[0];
    const int* ei = (const int*)d_in[1];
    const int* src = ei;            // edge_index[0]
    const int* dst = ei + NE;       // edge_index[1]
    const int* gidx = (const int*)d_in[2];
    const float* W1 = (const float*)d_in[3];
    const float* b1 = (const float*)d_in[4];
    const float* W2 = (const float*)d_in[5];
    const float* b2 = (const float*)d_in[6];
    const float* W3 = (const float*)d_in[7];
    const float* b3 = (const float*)d_in[8];
    const float* W4 = (const float*)d_in[9];
    const float* b4 = (const float*)d_in[10];
    const float* gamma = (const float*)d_in[11];
    const float* beta = (const float*)d_in[12];
    float* out = (float*)d_out;

    char* w = (char*)d_ws;
    auto take = [&](size_t bytes) {
        char* p = w;
        w += (bytes + 255) & ~size_t(255);
        return p;
    };
    int* counts = (int*)take((size_t)NN * 4);
    int* offsets = (int*)take((size_t)(NN + 1) * 4);
    int* cursor = (int*)take((size_t)NN * 4);
    int* bsum = (int*)take(512);
    int* csr = (int*)take((size_t)NE * 4);
    float* z1 = (float*)take((size_t)NN * DH * 4);
    float* pooled = (float*)take((size_t)NG * DH * 4);
    float* meanb = (float*)take(DH * 4);
    float* rstdb = (float*)take(DH * 4);

    k_zero<<<(NN + 255) / 256, 256, 0, stream>>>(counts, pooled);
    k_hist<<<(NE + 255) / 256, 256, 0, stream>>>(dst, counts);
    k_scan_blocks<<<NB_SCAN, 256, 0, stream>>>(counts, offsets, bsum);
    k_scan_bsum<<<1, 128, 0, stream>>>(bsum);
    k_add_base<<<(NN + 255) / 256, 256, 0, stream>>>(offsets, bsum, cursor);
    k_fill<<<(NE + 255) / 256, 256, 0, stream>>>(src, dst, cursor, csr);

    k_agg_mm<1, 0><<<NN / 16, 256, 0, stream>>>(x, W1, b1, offsets, csr, nullptr, z1, nullptr);
    k_agg_mm<0, 1><<<NN / 16, 256, 0, stream>>>(z1, W2, b2, offsets, csr, gidx, nullptr, pooled);

    k_bnstats<<<DH, 64, 0, stream>>>(pooled, meanb, rstdb);
    k_tail<<<NG, 128, 0, stream>>>(pooled, meanb, rstdb, gamma, beta, W3, b3, W4, b4, out);
}

// Round 3
// 697.056 us; speedup vs baseline: 1.1380x; 1.1380x over previous
//
#include <hip/hip_runtime.h>
#include <math.h>

#define NN 100000      // nodes
#define NE 1600000     // edges
#define DH 128         // feature dim
#define NG 512         // graphs
#define NC 10          // classes
#define NB_SCAN 98     // ceil(NN/1024)

// ---------------- CSR build ----------------

__global__ void k_zero(int* __restrict__ counts, float* __restrict__ pooled) {
    int i = blockIdx.x * 256 + threadIdx.x;
    if (i < NN) counts[i] = 0;
    if (i < NG * DH) pooled[i] = 0.f;
}

__global__ void k_hist(const int* __restrict__ dst, int* __restrict__ counts) {
    int e = blockIdx.x * 256 + threadIdx.x;
    if (e < NE) atomicAdd(&counts[dst[e]], 1);
}

// each block scans 1024 counts (256 thr x 4), writes exclusive offsets + block sum
__global__ void k_scan_blocks(const int* __restrict__ counts, int* __restrict__ offsets,
                              int* __restrict__ bsum) {
    __shared__ int sd[256];
    int t = threadIdx.x;
    int base = blockIdx.x * 1024 + t * 4;
    int v0 = (base + 0 < NN) ? counts[base + 0] : 0;
    int v1 = (base + 1 < NN) ? counts[base + 1] : 0;
    int v2 = (base + 2 < NN) ? counts[base + 2] : 0;
    int v3 = (base + 3 < NN) ? counts[base + 3] : 0;
    int s = v0 + v1 + v2 + v3;
    sd[t] = s;
    __syncthreads();
    for (int off = 1; off < 256; off <<= 1) {
        int x = (t >= off) ? sd[t - off] : 0;
        __syncthreads();
        sd[t] += x;
        __syncthreads();
    }
    int run = sd[t] - s;   // exclusive prefix of this thread's 4 elems
    if (base + 0 < NN) offsets[base + 0] = run; run += v0;
    if (base + 1 < NN) offsets[base + 1] = run; run += v1;
    if (base + 2 < NN) offsets[base + 2] = run; run += v2;
    if (base + 3 < NN) offsets[base + 3] = run; run += v3;
    if (t == 255) bsum[blockIdx.x] = run;  // block total
}

__global__ void k_scan_bsum(int* __restrict__ bsum) {
    __shared__ int sd[128];
    int t = threadIdx.x;
    int v = (t < NB_SCAN) ? bsum[t] : 0;
    sd[t] = v;
    __syncthreads();
    for (int off = 1; off < 128; off <<= 1) {
        int x = (t >= off) ? sd[t - off] : 0;
        __syncthreads();
        sd[t] += x;
        __syncthreads();
    }
    if (t < NB_SCAN) bsum[t] = sd[t] - v;  // exclusive
}

__global__ void k_add_base(int* __restrict__ offsets, const int* __restrict__ bsum,
                           int* __restrict__ cursor) {
    int i = blockIdx.x * 256 + threadIdx.x;
    if (i < NN) {
        int o = offsets[i] + bsum[i >> 10];
        offsets[i] = o;
        cursor[i] = o;
    }
    if (i == 0) offsets[NN] = NE;
}

__global__ void k_fill(const int* __restrict__ src, const int* __restrict__ dst,
                       int* __restrict__ cursor, int* __restrict__ csr) {
    int e = blockIdx.x * 256 + threadIdx.x;
    if (e < NE) {
        int d = dst[e];
        int p = atomicAdd(&cursor[d], 1);
        csr[p] = src[e];
    }
}

// ---------------- gather/aggregate: out[n] = in[n] + sum_{s in N(n)} in[s] ----
// No LDS -> high occupancy. 8 nodes/block (32 lanes x float4 per node).
// Edges unrolled x8; masked slots clamp to csr[e1-1] (row already in flight ->
// L1 hit, no wasted fabric fetch).

__global__ __launch_bounds__(256, 6) void k_agg(
    const float* __restrict__ in, const int* __restrict__ offs,
    const int* __restrict__ csr, float* __restrict__ outA) {
    int t = threadIdx.x;
    int lane = t & 31;
    int node = blockIdx.x * 8 + (t >> 5);
    const float4* in4 = (const float4*)in;
    float4 a = in4[(size_t)node * 32 + lane];   // self loop
    int e0 = offs[node], e1 = offs[node + 1];
    int elast = e1 - 1;
    for (int e = e0; e < e1; e += 8) {
        int idx[8];
        float m[8];
#pragma unroll
        for (int i = 0; i < 8; ++i) {
            int ei = e + i;
            int ec = ei < elast ? ei : elast;   // clamp: masked slots re-read hot row
            idx[i] = csr[ec];
            m[i] = (ei < e1) ? 1.f : 0.f;
        }
        float4 v[8];
#pragma unroll
        for (int i = 0; i < 8; ++i) v[i] = in4[(size_t)idx[i] * 32 + lane];
#pragma unroll
        for (int i = 0; i < 8; ++i) {
            a.x = fmaf(m[i], v[i].x, a.x);
            a.y = fmaf(m[i], v[i].y, a.y);
            a.z = fmaf(m[i], v[i].z, a.z);
            a.w = fmaf(m[i], v[i].w, a.w);
        }
    }
    ((float4*)outA)[(size_t)node * 32 + lane] = a;
}

// ---------------- matvec: out = A @ W + b (+relu / +pool) --------------------
// 32 nodes/block, 256 threads. Register blocking 4 nodes x 4 channels/thread:
// per 4 k-steps: 8 x ds_read_b128 for 64 FMAs = 2 LDS bytes/FMA.

__device__ __forceinline__ void fma4(float4& acc, float s, const float4& wv) {
    acc.x = fmaf(s, wv.x, acc.x);
    acc.y = fmaf(s, wv.y, acc.y);
    acc.z = fmaf(s, wv.z, acc.z);
    acc.w = fmaf(s, wv.w, acc.w);
}

template <int RELU, int POOL>
__global__ __launch_bounds__(256, 2) void k_mm(
    const float* __restrict__ A, const float* __restrict__ W,
    const float* __restrict__ bias, const int* __restrict__ gidx,
    float* __restrict__ out, float* __restrict__ pooled) {
    __shared__ __align__(16) float sW[DH * DH];     // 64 KB
    __shared__ __align__(16) float sA[32 * DH];     // 16 KB
    int t = threadIdx.x;
    int node0 = blockIdx.x * 32;
    {
        const float4* W4g = (const float4*)W;
        float4* sW4 = (float4*)sW;
        for (int i = t; i < DH * DH / 4; i += 256) sW4[i] = W4g[i];
        const float4* A4g = (const float4*)A + (size_t)node0 * 32;
        float4* sA4 = (float4*)sA;
        for (int i = t; i < 32 * DH / 4; i += 256) sA4[i] = A4g[i];
    }
    __syncthreads();

    int c4 = t & 31;          // channel quad: c0 = 4*c4
    int n0 = (t >> 5) * 4;    // first of 4 nodes
    const float4* sA4 = (const float4*)sA;
    const float4* sW4 = (const float4*)sW;
    float4 bv = ((const float4*)bias)[c4];
    float4 acc0 = bv, acc1 = bv, acc2 = bv, acc3 = bv;

#pragma unroll 2
    for (int kc = 0; kc < DH / 4; ++kc) {
        float4 a0 = sA4[(n0 + 0) * 32 + kc];
        float4 a1 = sA4[(n0 + 1) * 32 + kc];
        float4 a2 = sA4[(n0 + 2) * 32 + kc];
        float4 a3 = sA4[(n0 + 3) * 32 + kc];
        float4 w0 = sW4[(4 * kc + 0) * 32 + c4];
        float4 w1 = sW4[(4 * kc + 1) * 32 + c4];
        float4 w2 = sW4[(4 * kc + 2) * 32 + c4];
        float4 w3 = sW4[(4 * kc + 3) * 32 + c4];
        fma4(acc0, a0.x, w0); fma4(acc0, a0.y, w1); fma4(acc0, a0.z, w2); fma4(acc0, a0.w, w3);
        fma4(acc1, a1.x, w0); fma4(acc1, a1.y, w1); fma4(acc1, a1.z, w2); fma4(acc1, a1.w, w3);
        fma4(acc2, a2.x, w0); fma4(acc2, a2.y, w1); fma4(acc2, a2.z, w2); fma4(acc2, a2.w, w3);
        fma4(acc3, a3.x, w0); fma4(acc3, a3.y, w1); fma4(acc3, a3.z, w2); fma4(acc3, a3.w, w3);
    }

    if (RELU) {
        acc0.x = fmaxf(acc0.x, 0.f); acc0.y = fmaxf(acc0.y, 0.f);
        acc0.z = fmaxf(acc0.z, 0.f); acc0.w = fmaxf(acc0.w, 0.f);
        acc1.x = fmaxf(acc1.x, 0.f); acc1.y = fmaxf(acc1.y, 0.f);
        acc1.z = fmaxf(acc1.z, 0.f); acc1.w = fmaxf(acc1.w, 0.f);
        acc2.x = fmaxf(acc2.x, 0.f); acc2.y = fmaxf(acc2.y, 0.f);
        acc2.z = fmaxf(acc2.z, 0.f); acc2.w = fmaxf(acc2.w, 0.f);
        acc3.x = fmaxf(acc3.x, 0.f); acc3.y = fmaxf(acc3.y, 0.f);
        acc3.z = fmaxf(acc3.w > 0.f ? acc3.z : acc3.z, 0.f); acc3.w = fmaxf(acc3.w, 0.f);
    }

    if (POOL) {
        __syncthreads();   // done reading A tile
        float4* sA4w = (float4*)sA;
        sA4w[(n0 + 0) * 32 + c4] = acc0;
        sA4w[(n0 + 1) * 32 + c4] = acc1;
        sA4w[(n0 + 2) * 32 + c4] = acc2;
        sA4w[(n0 + 3) * 32 + c4] = acc3;
        __syncthreads();
        if (t < DH) {   // run-length reduce over sorted gidx, 1 channel/thread
            int gprev = gidx[node0];
            float run = 0.f;
            for (int p = 0; p < 32; ++p) {
                int g = gidx[node0 + p];
                if (g != gprev) {
                    atomicAdd(&pooled[gprev * DH + t], run);
                    run = 0.f;
                    gprev = g;
                }
                run += sA[p * DH + t];
            }
            atomicAdd(&pooled[gprev * DH + t], run);
        }
    } else {
        float4* out4 = (float4*)out;
        out4[(size_t)(node0 + n0 + 0) * 32 + c4] = acc0;
        out4[(size_t)(node0 + n0 + 1) * 32 + c4] = acc1;
        out4[(size_t)(node0 + n0 + 2) * 32 + c4] = acc2;
        out4[(size_t)(node0 + n0 + 3) * 32 + c4] = acc3;
    }
}

// ---------------- batchnorm stats ----------------

__global__ void k_bnstats(const float* __restrict__ pooled, float* __restrict__ mean,
                          float* __restrict__ rstd) {
    int c = blockIdx.x;    // 128 blocks, one per channel
    int l = threadIdx.x;   // 64 threads
    float s = 0.f, s2 = 0.f;
    for (int g = l; g < NG; g += 64) {
        float v = pooled[g * DH + c];
        s += v;
        s2 += v * v;
    }
#pragma unroll
    for (int off = 32; off > 0; off >>= 1) {
        s += __shfl_down(s, off, 64);
        s2 += __shfl_down(s2, off, 64);
    }
    if (l == 0) {
        float m = s * (1.f / NG);
        float var = s2 * (1.f / NG) - m * m;
        mean[c] = m;
        rstd[c] = rsqrtf(var + 1e-5f);
    }
}

// ---------------- BN + W3 + relu + W4 + log_softmax ----------------

__global__ __launch_bounds__(128) void k_tail(
    const float* __restrict__ pooled, const float* __restrict__ mean,
    const float* __restrict__ rstd, const float* __restrict__ gamma,
    const float* __restrict__ beta, const float* __restrict__ W3,
    const float* __restrict__ b3, const float* __restrict__ W4,
    const float* __restrict__ b4, float* __restrict__ out) {
    __shared__ __align__(16) float sW[DH * DH];
    __shared__ float sg[DH];
    __shared__ float sz[DH];
    __shared__ float slog[NC];
    __shared__ float slse;
    int g = blockIdx.x, t = threadIdx.x;
    {
        const float4* W34 = (const float4*)W3;
        float4* sW4 = (float4*)sW;
        for (int i = t; i < DH * DH / 4; i += 128) sW4[i] = W34[i];
    }
    float v = pooled[g * DH + t];
    v = (v - mean[t]) * rstd[t] * gamma[t] + beta[t];
    sg[t] = v;
    __syncthreads();
    float acc = b3[t];
#pragma unroll 4
    for (int k = 0; k < DH; ++k) acc = fmaf(sg[k], sW[k * DH + t], acc);
    sz[t] = fmaxf(acc, 0.f);
    __syncthreads();
    if (t < NC) {
        float a = b4[t];
        for (int k = 0; k < DH; ++k) a = fmaf(sz[k], W4[k * NC + t], a);
        slog[t] = a;
    }
    __syncthreads();
    if (t == 0) {
        float mx = slog[0];
        for (int j = 1; j < NC; ++j) mx = fmaxf(mx, slog[j]);
        float se = 0.f;
        for (int j = 0; j < NC; ++j) se += expf(slog[j] - mx);
        slse = mx + logf(se);
    }
    __syncthreads();
    if (t < NC) out[g * NC + t] = slog[t] - slse;
}

// ---------------- launch ----------------

extern "C" void kernel_launch(void* const* d_in, const int* in_sizes, int n_in,
                              void* d_out, int out_size, void* d_ws, size_t ws_size,
                              hipStream_t stream) {
    const float* x = (const float*)d_in[0];
    const int* ei = (const int*)d_in[1];
    const int* src = ei;            // edge_index[0]
    const int* dst = ei + NE;       // edge_index[1]
    const int* gidx = (const int*)d_in[2];
    const float* W1 = (const float*)d_in[3];
    const float* b1 = (const float*)d_in[4];
    const float* W2 = (const float*)d_in[5];
    const float* b2 = (const float*)d_in[6];
    const float* W3 = (const float*)d_in[7];
    const float* b3 = (const float*)d_in[8];
    const float* W4 = (const float*)d_in[9];
    const float* b4 = (const float*)d_in[10];
    const float* gamma = (const float*)d_in[11];
    const float* beta = (const float*)d_in[12];
    float* out = (float*)d_out;

    char* w = (char*)d_ws;
    auto take = [&](size_t bytes) {
        char* p = w;
        w += (bytes + 255) & ~size_t(255);
        return p;
    };
    int* counts = (int*)take((size_t)NN * 4);
    int* offsets = (int*)take((size_t)(NN + 1) * 4);
    int* cursor = (int*)take((size_t)NN * 4);
    int* bsum = (int*)take(512);
    int* csr = (int*)take((size_t)NE * 4);
    float* bufA = (float*)take((size_t)NN * DH * 4);   // agg output
    float* bufB = (float*)take((size_t)NN * DH * 4);   // z1
    float* pooled = (float*)take((size_t)NG * DH * 4);
    float* meanb = (float*)take(DH * 4);
    float* rstdb = (float*)take(DH * 4);

    k_zero<<<(NN + 255) / 256, 256, 0, stream>>>(counts, pooled);
    k_hist<<<(NE + 255) / 256, 256, 0, stream>>>(dst, counts);
    k_scan_blocks<<<NB_SCAN, 256, 0, stream>>>(counts, offsets, bsum);
    k_scan_bsum<<<1, 128, 0, stream>>>(bsum);
    k_add_base<<<(NN + 255) / 256, 256, 0, stream>>>(offsets, bsum, cursor);
    k_fill<<<(NE + 255) / 256, 256, 0, stream>>>(src, dst, cursor, csr);

    // layer 1: agg(x) -> bufA ; bufA @ W1 + b1, relu -> bufB
    k_agg<<<NN / 8, 256, 0, stream>>>(x, offsets, csr, bufA);
    k_mm<1, 0><<<NN / 32, 256, 0, stream>>>(bufA, W1, b1, nullptr, bufB, nullptr);
    // layer 2: agg(bufB) -> bufA ; bufA @ W2 + b2, pool -> pooled
    k_agg<<<NN / 8, 256, 0, stream>>>(bufB, offsets, csr, bufA);
    k_mm<0, 1><<<NN / 32, 256, 0, stream>>>(bufA, W2, b2, gidx, nullptr, pooled);

    k_bnstats<<<DH, 64, 0, stream>>>(pooled, meanb, rstdb);
    k_tail<<<NG, 128, 0, stream>>>(pooled, meanb, rstdb, gamma, beta, W3, b3, W4, b4, out);
}

// Round 4
// 613.790 us; speedup vs baseline: 1.2924x; 1.1357x over previous
//
#include <hip/hip_runtime.h>
#include <math.h>

#define NN 100000      // nodes
#define NE 1600000     // edges
#define DH 128         // feature dim
#define NG 512         // graphs
#define NC 10          // classes
#define NB_SCAN 98     // ceil(NN/1024)
#define NSEG 8         // XCD partitions for hist/fill
#define SEGN 12500     // nodes per segment
#define CHE 8192       // edges per chunk in partitioned hist/fill
#define NCH 196        // ceil(NE/CHE)

// ---------------- zero ----------------

__global__ void k_zero(int* __restrict__ counts, float* __restrict__ pp8,
                       int* __restrict__ cnt) {
    int i = blockIdx.x * 256 + threadIdx.x;
    if (i < NN) counts[i] = 0;
    if (i < NSEG * NG * DH) pp8[i] = 0.f;
    if (i < NG) cnt[i] = 0;
}

// ---------------- XCD-partitioned histogram over dst ----------------
// block = (chunk, seg): seg owns dst range [seg*SEGN, seg*SEGN+SEGN).
// With blockIdx%8 -> XCD round-robin, counts lines stay in the local L2.
// Correctness independent of mapping: each edge processed by exactly one block.

__global__ __launch_bounds__(256) void k_hist_part(const int* __restrict__ dst,
                                                   int* __restrict__ counts) {
    int seg = blockIdx.x & 7;
    int chunk = blockIdx.x >> 3;
    int lo = seg * SEGN, hi = lo + SEGN;
    int e0 = chunk * CHE;
    int e1 = e0 + CHE < NE ? e0 + CHE : NE;
    for (int e = e0 + threadIdx.x; e < e1; e += 256) {
        int d = dst[e];
        if (d >= lo && d < hi) atomicAdd(&counts[d], 1);
    }
}

// each block scans 1024 counts (256 thr x 4), writes exclusive offsets + block sum
__global__ void k_scan_blocks(const int* __restrict__ counts, int* __restrict__ offsets,
                              int* __restrict__ bsum) {
    __shared__ int sd[256];
    int t = threadIdx.x;
    int base = blockIdx.x * 1024 + t * 4;
    int v0 = (base + 0 < NN) ? counts[base + 0] : 0;
    int v1 = (base + 1 < NN) ? counts[base + 1] : 0;
    int v2 = (base + 2 < NN) ? counts[base + 2] : 0;
    int v3 = (base + 3 < NN) ? counts[base + 3] : 0;
    int s = v0 + v1 + v2 + v3;
    sd[t] = s;
    __syncthreads();
    for (int off = 1; off < 256; off <<= 1) {
        int x = (t >= off) ? sd[t - off] : 0;
        __syncthreads();
        sd[t] += x;
        __syncthreads();
    }
    int run = sd[t] - s;
    if (base + 0 < NN) offsets[base + 0] = run; run += v0;
    if (base + 1 < NN) offsets[base + 1] = run; run += v1;
    if (base + 2 < NN) offsets[base + 2] = run; run += v2;
    if (base + 3 < NN) offsets[base + 3] = run; run += v3;
    if (t == 255) bsum[blockIdx.x] = run;
}

__global__ void k_scan_bsum(int* __restrict__ bsum) {
    __shared__ int sd[128];
    int t = threadIdx.x;
    int v = (t < NB_SCAN) ? bsum[t] : 0;
    sd[t] = v;
    __syncthreads();
    for (int off = 1; off < 128; off <<= 1) {
        int x = (t >= off) ? sd[t - off] : 0;
        __syncthreads();
        sd[t] += x;
        __syncthreads();
    }
    if (t < NB_SCAN) bsum[t] = sd[t] - v;
}

__global__ void k_add_base(int* __restrict__ offsets, const int* __restrict__ bsum,
                           int* __restrict__ cursor) {
    int i = blockIdx.x * 256 + threadIdx.x;
    if (i < NN) {
        int o = offsets[i] + bsum[i >> 10];
        offsets[i] = o;
        cursor[i] = o;
    }
    if (i == 0) offsets[NN] = NE;
}

// ---------------- XCD-partitioned CSR fill ----------------

__global__ __launch_bounds__(256) void k_fill_part(const int* __restrict__ src,
                                                   const int* __restrict__ dst,
                                                   int* __restrict__ cursor,
                                                   int* __restrict__ csr) {
    int seg = blockIdx.x & 7;
    int chunk = blockIdx.x >> 3;
    int lo = seg * SEGN, hi = lo + SEGN;
    int e0 = chunk * CHE;
    int e1 = e0 + CHE < NE ? e0 + CHE : NE;
    for (int e = e0 + threadIdx.x; e < e1; e += 256) {
        int d = dst[e];
        if (d >= lo && d < hi) {
            int p = atomicAdd(&cursor[d], 1);
            csr[p] = src[e];
        }
    }
}

// ---------------- per-graph node counts (idx is sorted -> run-length) --------

__global__ void k_cnt(const int* __restrict__ gidx, int* __restrict__ cnt) {
    int t = threadIdx.x;
    int n0 = blockIdx.x * 1024 + t * 4;
    if (n0 >= NN) return;
    int g = gidx[n0];
    int run = 1;
    for (int j = 1; j < 4; ++j) {
        int n = n0 + j;
        if (n < NN) {
            int gg = gidx[n];
            if (gg == g) {
                run++;
            } else {
                atomicAdd(&cnt[g], run);
                g = gg;
                run = 1;
            }
        }
    }
    atomicAdd(&cnt[g], run);
}

// ---------------- gather/aggregate ----------------
// MODE 0: out[n] = in[n] + sum_neighbors                    (plain)
// MODE 1: out[n] = relu(in[n] + sum_neighbors + bias)       (layer-1 epilogue)

template <int MODE>
__global__ __launch_bounds__(256, 6) void k_agg(
    const float* __restrict__ in, const int* __restrict__ offs,
    const int* __restrict__ csr, const float* __restrict__ bias,
    float* __restrict__ outA) {
    int t = threadIdx.x;
    int lane = t & 31;
    int node = blockIdx.x * 8 + (t >> 5);
    const float4* in4 = (const float4*)in;
    float4 a = in4[(size_t)node * 32 + lane];   // self loop
    int e0 = offs[node], e1 = offs[node + 1];
    int elast = e1 - 1;
    for (int e = e0; e < e1; e += 8) {
        int idx[8];
        float m[8];
#pragma unroll
        for (int i = 0; i < 8; ++i) {
            int ei = e + i;
            int ec = ei < elast ? ei : elast;   // clamp: masked slots re-read hot row
            idx[i] = csr[ec];
            m[i] = (ei < e1) ? 1.f : 0.f;
        }
        float4 v[8];
#pragma unroll
        for (int i = 0; i < 8; ++i) v[i] = in4[(size_t)idx[i] * 32 + lane];
#pragma unroll
        for (int i = 0; i < 8; ++i) {
            a.x = fmaf(m[i], v[i].x, a.x);
            a.y = fmaf(m[i], v[i].y, a.y);
            a.z = fmaf(m[i], v[i].z, a.z);
            a.w = fmaf(m[i], v[i].w, a.w);
        }
    }
    if (MODE == 1) {
        float4 b = ((const float4*)bias)[lane];
        a.x = fmaxf(a.x + b.x, 0.f);
        a.y = fmaxf(a.y + b.y, 0.f);
        a.z = fmaxf(a.z + b.z, 0.f);
        a.w = fmaxf(a.w + b.w, 0.f);
    }
    ((float4*)outA)[(size_t)node * 32 + lane] = a;
}

// ---------------- gather/aggregate + pooled-pre accumulation ----------------
// pooled_pre[g] += agg(z1)[n] for nodes n of graph g. 8 nodes/block staged in
// LDS, run-length reduced over sorted gidx, atomics into XCD-private copy.

__global__ __launch_bounds__(256, 6) void k_agg_pool(
    const float* __restrict__ in, const int* __restrict__ offs,
    const int* __restrict__ csr, const int* __restrict__ gidx,
    float* __restrict__ pp8) {
    __shared__ __align__(16) float sA[8][DH];
    int t = threadIdx.x;
    int lane = t & 31;
    int p = t >> 5;
    int node0 = blockIdx.x * 8;
    int node = node0 + p;
    const float4* in4 = (const float4*)in;
    float4 a = in4[(size_t)node * 32 + lane];
    int e0 = offs[node], e1 = offs[node + 1];
    int elast = e1 - 1;
    for (int e = e0; e < e1; e += 8) {
        int idx[8];
        float m[8];
#pragma unroll
        for (int i = 0; i < 8; ++i) {
            int ei = e + i;
            int ec = ei < elast ? ei : elast;
            idx[i] = csr[ec];
            m[i] = (ei < e1) ? 1.f : 0.f;
        }
        float4 v[8];
#pragma unroll
        for (int i = 0; i < 8; ++i) v[i] = in4[(size_t)idx[i] * 32 + lane];
#pragma unroll
        for (int i = 0; i < 8; ++i) {
            a.x = fmaf(m[i], v[i].x, a.x);
            a.y = fmaf(m[i], v[i].y, a.y);
            a.z = fmaf(m[i], v[i].z, a.z);
            a.w = fmaf(m[i], v[i].w, a.w);
        }
    }
    ((float4*)&sA[p][0])[lane] = a;
    __syncthreads();
    if (t < DH) {
        float* pp = pp8 + (size_t)(blockIdx.x & 7) * NG * DH;
        int gprev = gidx[node0];
        float run = 0.f;
        for (int q = 0; q < 8; ++q) {
            int g = gidx[node0 + q];
            if (g != gprev) {
                atomicAdd(&pp[gprev * DH + t], run);
                run = 0.f;
                gprev = g;
            }
            run += sA[q][t];
        }
        atomicAdd(&pp[gprev * DH + t], run);
    }
}

// ---------------- dense matvec: out = A @ W (+bias, +relu) -------------------

__device__ __forceinline__ void fma4(float4& acc, float s, const float4& wv) {
    acc.x = fmaf(s, wv.x, acc.x);
    acc.y = fmaf(s, wv.y, acc.y);
    acc.z = fmaf(s, wv.z, acc.z);
    acc.w = fmaf(s, wv.w, acc.w);
}

template <int RELU, int HASB>
__global__ __launch_bounds__(256, 2) void k_mm(
    const float* __restrict__ A, const float* __restrict__ W,
    const float* __restrict__ bias, float* __restrict__ out) {
    __shared__ __align__(16) float sW[DH * DH];     // 64 KB
    __shared__ __align__(16) float sA[32 * DH];     // 16 KB
    int t = threadIdx.x;
    int node0 = blockIdx.x * 32;
    {
        const float4* W4g = (const float4*)W;
        float4* sW4 = (float4*)sW;
        for (int i = t; i < DH * DH / 4; i += 256) sW4[i] = W4g[i];
        const float4* A4g = (const float4*)A + (size_t)node0 * 32;
        float4* sA4 = (float4*)sA;
        for (int i = t; i < 32 * DH / 4; i += 256) sA4[i] = A4g[i];
    }
    __syncthreads();

    int c4 = t & 31;
    int n0 = (t >> 5) * 4;
    const float4* sA4 = (const float4*)sA;
    const float4* sW4 = (const float4*)sW;
    float4 bv;
    if (HASB) bv = ((const float4*)bias)[c4];
    else { bv.x = 0.f; bv.y = 0.f; bv.z = 0.f; bv.w = 0.f; }
    float4 acc0 = bv, acc1 = bv, acc2 = bv, acc3 = bv;

#pragma unroll 2
    for (int kc = 0; kc < DH / 4; ++kc) {
        float4 a0 = sA4[(n0 + 0) * 32 + kc];
        float4 a1 = sA4[(n0 + 1) * 32 + kc];
        float4 a2 = sA4[(n0 + 2) * 32 + kc];
        float4 a3 = sA4[(n0 + 3) * 32 + kc];
        float4 w0 = sW4[(4 * kc + 0) * 32 + c4];
        float4 w1 = sW4[(4 * kc + 1) * 32 + c4];
        float4 w2 = sW4[(4 * kc + 2) * 32 + c4];
        float4 w3 = sW4[(4 * kc + 3) * 32 + c4];
        fma4(acc0, a0.x, w0); fma4(acc0, a0.y, w1); fma4(acc0, a0.z, w2); fma4(acc0, a0.w, w3);
        fma4(acc1, a1.x, w0); fma4(acc1, a1.y, w1); fma4(acc1, a1.z, w2); fma4(acc1, a1.w, w3);
        fma4(acc2, a2.x, w0); fma4(acc2, a2.y, w1); fma4(acc2, a2.z, w2); fma4(acc2, a2.w, w3);
        fma4(acc3, a3.x, w0); fma4(acc3, a3.y, w1); fma4(acc3, a3.z, w2); fma4(acc3, a3.w, w3);
    }

    if (RELU) {
        acc0.x = fmaxf(acc0.x, 0.f); acc0.y = fmaxf(acc0.y, 0.f);
        acc0.z = fmaxf(acc0.z, 0.f); acc0.w = fmaxf(acc0.w, 0.f);
        acc1.x = fmaxf(acc1.x, 0.f); acc1.y = fmaxf(acc1.y, 0.f);
        acc1.z = fmaxf(acc1.z, 0.f); acc1.w = fmaxf(acc1.w, 0.f);
        acc2.x = fmaxf(acc2.x, 0.f); acc2.y = fmaxf(acc2.y, 0.f);
        acc2.z = fmaxf(acc2.z, 0.f); acc2.w = fmaxf(acc2.w, 0.f);
        acc3.x = fmaxf(acc3.x, 0.f); acc3.y = fmaxf(acc3.y, 0.f);
        acc3.z = fmaxf(acc3.z, 0.f); acc3.w = fmaxf(acc3.w, 0.f);
    }

    float4* out4 = (float4*)out;
    out4[(size_t)(node0 + n0 + 0) * 32 + c4] = acc0;
    out4[(size_t)(node0 + n0 + 1) * 32 + c4] = acc1;
    out4[(size_t)(node0 + n0 + 2) * 32 + c4] = acc2;
    out4[(size_t)(node0 + n0 + 3) * 32 + c4] = acc3;
}

// ---------------- pooled = (sum of pp8 copies) @ W2 + cnt*b2 ----------------

__global__ __launch_bounds__(256, 2) void k_pool_mm(
    const float* __restrict__ pp8, const float* __restrict__ W,
    const float* __restrict__ bias, const int* __restrict__ cnt,
    float* __restrict__ pooled) {
    __shared__ __align__(16) float sW[DH * DH];
    __shared__ __align__(16) float sA[32 * DH];
    int t = threadIdx.x;
    int g0 = blockIdx.x * 32;
    {
        const float4* W4g = (const float4*)W;
        float4* sW4 = (float4*)sW;
        for (int i = t; i < DH * DH / 4; i += 256) sW4[i] = W4g[i];
        const float4* P4 = (const float4*)pp8;
        float4* sA4 = (float4*)sA;
        for (int i = t; i < 32 * DH / 4; i += 256) {
            float4 s;
            s.x = 0.f; s.y = 0.f; s.z = 0.f; s.w = 0.f;
#pragma unroll
            for (int c = 0; c < NSEG; ++c) {
                float4 v = P4[(size_t)c * NG * DH / 4 + (size_t)g0 * DH / 4 + i];
                s.x += v.x; s.y += v.y; s.z += v.z; s.w += v.w;
            }
            sA4[i] = s;
        }
    }
    __syncthreads();

    int c4 = t & 31;
    int n0 = (t >> 5) * 4;
    const float4* sA4 = (const float4*)sA;
    const float4* sW4 = (const float4*)sW;
    float4 acc0, acc1, acc2, acc3;
    acc0.x = acc0.y = acc0.z = acc0.w = 0.f;
    acc1 = acc0; acc2 = acc0; acc3 = acc0;

#pragma unroll 2
    for (int kc = 0; kc < DH / 4; ++kc) {
        float4 a0 = sA4[(n0 + 0) * 32 + kc];
        float4 a1 = sA4[(n0 + 1) * 32 + kc];
        float4 a2 = sA4[(n0 + 2) * 32 + kc];
        float4 a3 = sA4[(n0 + 3) * 32 + kc];
        float4 w0 = sW4[(4 * kc + 0) * 32 + c4];
        float4 w1 = sW4[(4 * kc + 1) * 32 + c4];
        float4 w2 = sW4[(4 * kc + 2) * 32 + c4];
        float4 w3 = sW4[(4 * kc + 3) * 32 + c4];
        fma4(acc0, a0.x, w0); fma4(acc0, a0.y, w1); fma4(acc0, a0.z, w2); fma4(acc0, a0.w, w3);
        fma4(acc1, a1.x, w0); fma4(acc1, a1.y, w1); fma4(acc1, a1.z, w2); fma4(acc1, a1.w, w3);
        fma4(acc2, a2.x, w0); fma4(acc2, a2.y, w1); fma4(acc2, a2.z, w2); fma4(acc2, a2.w, w3);
        fma4(acc3, a3.x, w0); fma4(acc3, a3.y, w1); fma4(acc3, a3.z, w2); fma4(acc3, a3.w, w3);
    }

    float4 b2v = ((const float4*)bias)[c4];
    float c0 = (float)cnt[g0 + n0 + 0];
    float c1 = (float)cnt[g0 + n0 + 1];
    float c2 = (float)cnt[g0 + n0 + 2];
    float c3 = (float)cnt[g0 + n0 + 3];
    fma4(acc0, c0, b2v);
    fma4(acc1, c1, b2v);
    fma4(acc2, c2, b2v);
    fma4(acc3, c3, b2v);

    float4* out4 = (float4*)pooled;
    out4[(size_t)(g0 + n0 + 0) * 32 + c4] = acc0;
    out4[(size_t)(g0 + n0 + 1) * 32 + c4] = acc1;
    out4[(size_t)(g0 + n0 + 2) * 32 + c4] = acc2;
    out4[(size_t)(g0 + n0 + 3) * 32 + c4] = acc3;
}

// ---------------- batchnorm stats ----------------

__global__ void k_bnstats(const float* __restrict__ pooled, float* __restrict__ mean,
                          float* __restrict__ rstd) {
    int c = blockIdx.x;
    int l = threadIdx.x;
    float s = 0.f, s2 = 0.f;
    for (int g = l; g < NG; g += 64) {
        float v = pooled[g * DH + c];
        s += v;
        s2 += v * v;
    }
#pragma unroll
    for (int off = 32; off > 0; off >>= 1) {
        s += __shfl_down(s, off, 64);
        s2 += __shfl_down(s2, off, 64);
    }
    if (l == 0) {
        float m = s * (1.f / NG);
        float var = s2 * (1.f / NG) - m * m;
        mean[c] = m;
        rstd[c] = rsqrtf(var + 1e-5f);
    }
}

// ---------------- BN + W3 + relu + W4 + log_softmax ----------------

__global__ __launch_bounds__(128) void k_tail(
    const float* __restrict__ pooled, const float* __restrict__ mean,
    const float* __restrict__ rstd, const float* __restrict__ gamma,
    const float* __restrict__ beta, const float* __restrict__ W3,
    const float* __restrict__ b3, const float* __restrict__ W4,
    const float* __restrict__ b4, float* __restrict__ out) {
    __shared__ __align__(16) float sW[DH * DH];
    __shared__ float sg[DH];
    __shared__ float sz[DH];
    __shared__ float slog[NC];
    __shared__ float slse;
    int g = blockIdx.x, t = threadIdx.x;
    {
        const float4* W34 = (const float4*)W3;
        float4* sW4 = (float4*)sW;
        for (int i = t; i < DH * DH / 4; i += 128) sW4[i] = W34[i];
    }
    float v = pooled[g * DH + t];
    v = (v - mean[t]) * rstd[t] * gamma[t] + beta[t];
    sg[t] = v;
    __syncthreads();
    float acc = b3[t];
#pragma unroll 4
    for (int k = 0; k < DH; ++k) acc = fmaf(sg[k], sW[k * DH + t], acc);
    sz[t] = fmaxf(acc, 0.f);
    __syncthreads();
    if (t < NC) {
        float a = b4[t];
        for (int k = 0; k < DH; ++k) a = fmaf(sz[k], W4[k * NC + t], a);
        slog[t] = a;
    }
    __syncthreads();
    if (t == 0) {
        float mx = slog[0];
        for (int j = 1; j < NC; ++j) mx = fmaxf(mx, slog[j]);
        float se = 0.f;
        for (int j = 0; j < NC; ++j) se += expf(slog[j] - mx);
        slse = mx + logf(se);
    }
    __syncthreads();
    if (t < NC) out[g * NC + t] = slog[t] - slse;
}

// ---------------- launch ----------------

extern "C" void kernel_launch(void* const* d_in, const int* in_sizes, int n_in,
                              void* d_out, int out_size, void* d_ws, size_t ws_size,
                              hipStream_t stream) {
    const float* x = (const float*)d_in[0];
    const int* ei = (const int*)d_in[1];
    const int* src = ei;            // edge_index[0]
    const int* dst = ei + NE;       // edge_index[1]
    const int* gidx = (const int*)d_in[2];
    const float* W1 = (const float*)d_in[3];
    const float* b1 = (const float*)d_in[4];
    const float* W2 = (const float*)d_in[5];
    const float* b2 = (const float*)d_in[6];
    const float* W3 = (const float*)d_in[7];
    const float* b3 = (const float*)d_in[8];
    const float* W4 = (const float*)d_in[9];
    const float* b4 = (const float*)d_in[10];
    const float* gamma = (const float*)d_in[11];
    const float* beta = (const float*)d_in[12];
    float* out = (float*)d_out;

    char* w = (char*)d_ws;
    auto take = [&](size_t bytes) {
        char* p = w;
        w += (bytes + 255) & ~size_t(255);
        return p;
    };
    int* counts = (int*)take((size_t)NN * 4);
    int* offsets = (int*)take((size_t)(NN + 1) * 4);
    int* cursor = (int*)take((size_t)NN * 4);
    int* bsum = (int*)take(512);
    int* csr = (int*)take((size_t)NE * 4);
    float* y = (float*)take((size_t)NN * DH * 4);     // x @ W1
    float* z1 = (float*)take((size_t)NN * DH * 4);    // relu(agg(y)+b1)
    float* pp8 = (float*)take((size_t)NSEG * NG * DH * 4);   // XCD-private pool acc
    int* cnt = (int*)take((size_t)NG * 4);
    float* pooled = (float*)take((size_t)NG * DH * 4);
    float* meanb = (float*)take(DH * 4);
    float* rstdb = (float*)take(DH * 4);

    // CSR build (dst-indexed), XCD-partitioned atomics
    k_zero<<<(NSEG * NG * DH + 255) / 256, 256, 0, stream>>>(counts, pp8, cnt);
    k_hist_part<<<NCH * NSEG, 256, 0, stream>>>(dst, counts);
    k_scan_blocks<<<NB_SCAN, 256, 0, stream>>>(counts, offsets, bsum);
    k_scan_bsum<<<1, 128, 0, stream>>>(bsum);
    k_add_base<<<(NN + 255) / 256, 256, 0, stream>>>(offsets, bsum, cursor);
    k_fill_part<<<NCH * NSEG, 256, 0, stream>>>(src, dst, cursor, csr);
    k_cnt<<<NB_SCAN, 256, 0, stream>>>(gidx, cnt);

    // layer 1: y = x@W1 (agg commutes with matmul); z1 = relu(agg(y)+b1)
    k_mm<0, 0><<<NN / 32, 256, 0, stream>>>(x, W1, nullptr, y);
    k_agg<1><<<NN / 8, 256, 0, stream>>>(y, offsets, csr, b1, z1);

    // layer 2: pooled_pre[g] = sum_{n in g} agg(z1)[n]; pooled = pre@W2 + cnt*b2
    k_agg_pool<<<NN / 8, 256, 0, stream>>>(z1, offsets, csr, gidx, pp8);
    k_pool_mm<<<NG / 32, 256, 0, stream>>>(pp8, W2, b2, cnt, pooled);

    k_bnstats<<<DH, 64, 0, stream>>>(pooled, meanb, rstdb);
    k_tail<<<NG, 128, 0, stream>>>(pooled, meanb, rstdb, gamma, beta, W3, b3, W4, b4, out);
}

// Round 5
// 516.069 us; speedup vs baseline: 1.5371x; 1.1894x over previous
//
#include <hip/hip_runtime.h>
#include <hip/hip_fp16.h>
#include <math.h>

#define NN 100000      // nodes
#define NE 1600000     // edges
#define DH 128         // feature dim
#define NG 512         // graphs
#define NC 10          // classes
#define NB_SCAN 98     // ceil(NN/1024)
#define NSEG 8         // XCD partitions for hist/fill
#define SEGN 12500     // nodes per segment
#define CHE 8192       // edges per chunk in partitioned hist/fill
#define NCH 196        // ceil(NE/CHE)

// ---------------- zero ----------------

__global__ void k_zero(int* __restrict__ counts, float* __restrict__ pp8,
                       int* __restrict__ cnt) {
    int i = blockIdx.x * 256 + threadIdx.x;
    if (i < NN) counts[i] = 0;
    if (i < NSEG * NG * DH) pp8[i] = 0.f;
    if (i < NG) cnt[i] = 0;
}

// ---------------- XCD-partitioned histogram over dst ----------------

__global__ __launch_bounds__(256) void k_hist_part(const int* __restrict__ dst,
                                                   int* __restrict__ counts) {
    int seg = blockIdx.x & 7;
    int chunk = blockIdx.x >> 3;
    int lo = seg * SEGN, hi = lo + SEGN;
    int e0 = chunk * CHE;
    int e1 = e0 + CHE < NE ? e0 + CHE : NE;
    for (int e = e0 + threadIdx.x; e < e1; e += 256) {
        int d = dst[e];
        if (d >= lo && d < hi) atomicAdd(&counts[d], 1);
    }
}

__global__ void k_scan_blocks(const int* __restrict__ counts, int* __restrict__ offsets,
                              int* __restrict__ bsum) {
    __shared__ int sd[256];
    int t = threadIdx.x;
    int base = blockIdx.x * 1024 + t * 4;
    int v0 = (base + 0 < NN) ? counts[base + 0] : 0;
    int v1 = (base + 1 < NN) ? counts[base + 1] : 0;
    int v2 = (base + 2 < NN) ? counts[base + 2] : 0;
    int v3 = (base + 3 < NN) ? counts[base + 3] : 0;
    int s = v0 + v1 + v2 + v3;
    sd[t] = s;
    __syncthreads();
    for (int off = 1; off < 256; off <<= 1) {
        int x = (t >= off) ? sd[t - off] : 0;
        __syncthreads();
        sd[t] += x;
        __syncthreads();
    }
    int run = sd[t] - s;
    if (base + 0 < NN) offsets[base + 0] = run; run += v0;
    if (base + 1 < NN) offsets[base + 1] = run; run += v1;
    if (base + 2 < NN) offsets[base + 2] = run; run += v2;
    if (base + 3 < NN) offsets[base + 3] = run; run += v3;
    if (t == 255) bsum[blockIdx.x] = run;
}

__global__ void k_scan_bsum(int* __restrict__ bsum) {
    __shared__ int sd[128];
    int t = threadIdx.x;
    int v = (t < NB_SCAN) ? bsum[t] : 0;
    sd[t] = v;
    __syncthreads();
    for (int off = 1; off < 128; off <<= 1) {
        int x = (t >= off) ? sd[t - off] : 0;
        __syncthreads();
        sd[t] += x;
        __syncthreads();
    }
    if (t < NB_SCAN) bsum[t] = sd[t] - v;
}

__global__ void k_add_base(int* __restrict__ offsets, const int* __restrict__ bsum,
                           int* __restrict__ cursor) {
    int i = blockIdx.x * 256 + threadIdx.x;
    if (i < NN) {
        int o = offsets[i] + bsum[i >> 10];
        offsets[i] = o;
        cursor[i] = o;
    }
    if (i == 0) offsets[NN] = NE;
}

__global__ __launch_bounds__(256) void k_fill_part(const int* __restrict__ src,
                                                   const int* __restrict__ dst,
                                                   int* __restrict__ cursor,
                                                   int* __restrict__ csr) {
    int seg = blockIdx.x & 7;
    int chunk = blockIdx.x >> 3;
    int lo = seg * SEGN, hi = lo + SEGN;
    int e0 = chunk * CHE;
    int e1 = e0 + CHE < NE ? e0 + CHE : NE;
    for (int e = e0 + threadIdx.x; e < e1; e += 256) {
        int d = dst[e];
        if (d >= lo && d < hi) {
            int p = atomicAdd(&cursor[d], 1);
            csr[p] = src[e];
        }
    }
}

// ---------------- per-graph node counts (idx is sorted -> run-length) --------

__global__ void k_cnt(const int* __restrict__ gidx, int* __restrict__ cnt) {
    int t = threadIdx.x;
    int n0 = blockIdx.x * 1024 + t * 4;
    if (n0 >= NN) return;
    int g = gidx[n0];
    int run = 1;
    for (int j = 1; j < 4; ++j) {
        int n = n0 + j;
        if (n < NN) {
            int gg = gidx[n];
            if (gg == g) {
                run++;
            } else {
                atomicAdd(&cnt[g], run);
                g = gg;
                run = 1;
            }
        }
    }
    atomicAdd(&cnt[g], run);
}

// ---------------- fp16 helpers ----------------

__device__ __forceinline__ void acc8(float* a, const uint4& v, float m) {
    float2 f;
    f = __half22float2(*(const __half2*)&v.x); a[0] = fmaf(m, f.x, a[0]); a[1] = fmaf(m, f.y, a[1]);
    f = __half22float2(*(const __half2*)&v.y); a[2] = fmaf(m, f.x, a[2]); a[3] = fmaf(m, f.y, a[3]);
    f = __half22float2(*(const __half2*)&v.z); a[4] = fmaf(m, f.x, a[4]); a[5] = fmaf(m, f.y, a[5]);
    f = __half22float2(*(const __half2*)&v.w); a[6] = fmaf(m, f.x, a[6]); a[7] = fmaf(m, f.y, a[7]);
}

// ---------------- gather (fp16 rows) + bias + relu -> fp16 out --------------
// 16 nodes/block, 16 lanes/node, 16 B/lane (dwordx4). Row = 256 B.

__global__ __launch_bounds__(256, 6) void k_agg_h(
    const __half* __restrict__ in, const int* __restrict__ offs,
    const int* __restrict__ csr, const float* __restrict__ bias,
    __half* __restrict__ outA) {
    int t = threadIdx.x;
    int lane = t & 15;
    int node = blockIdx.x * 16 + (t >> 4);
    const uint4* in4 = (const uint4*)in;   // 16 uint4 per row
    float a[8];
#pragma unroll
    for (int j = 0; j < 8; ++j) a[j] = 0.f;
    uint4 sv = in4[(size_t)node * 16 + lane];
    acc8(a, sv, 1.f);                      // self loop
    int e0 = offs[node], e1 = offs[node + 1];
    int elast = e1 - 1;
    for (int e = e0; e < e1; e += 8) {
        int idx[8];
        float m[8];
#pragma unroll
        for (int i = 0; i < 8; ++i) {
            int ei = e + i;
            int ec = ei < elast ? ei : elast;   // clamp: masked slots re-read hot row
            idx[i] = csr[ec];
            m[i] = (ei < e1) ? 1.f : 0.f;
        }
        uint4 v[8];
#pragma unroll
        for (int i = 0; i < 8; ++i) v[i] = in4[(size_t)idx[i] * 16 + lane];
#pragma unroll
        for (int i = 0; i < 8; ++i) acc8(a, v[i], m[i]);
    }
    float4 b0 = ((const float4*)bias)[lane * 2];
    float4 b1v = ((const float4*)bias)[lane * 2 + 1];
    a[0] = fmaxf(a[0] + b0.x, 0.f);  a[1] = fmaxf(a[1] + b0.y, 0.f);
    a[2] = fmaxf(a[2] + b0.z, 0.f);  a[3] = fmaxf(a[3] + b0.w, 0.f);
    a[4] = fmaxf(a[4] + b1v.x, 0.f); a[5] = fmaxf(a[5] + b1v.y, 0.f);
    a[6] = fmaxf(a[6] + b1v.z, 0.f); a[7] = fmaxf(a[7] + b1v.w, 0.f);
    uint4 o;
    *(__half2*)&o.x = __floats2half2_rn(a[0], a[1]);
    *(__half2*)&o.y = __floats2half2_rn(a[2], a[3]);
    *(__half2*)&o.z = __floats2half2_rn(a[4], a[5]);
    *(__half2*)&o.w = __floats2half2_rn(a[6], a[7]);
    ((uint4*)outA)[(size_t)node * 16 + lane] = o;
}

// ---------------- gather (fp16 rows) + per-graph pooling --------------------

__global__ __launch_bounds__(256, 6) void k_agg_pool_h(
    const __half* __restrict__ in, const int* __restrict__ offs,
    const int* __restrict__ csr, const int* __restrict__ gidx,
    float* __restrict__ pp8) {
    __shared__ __align__(16) float sA[16][DH];
    int t = threadIdx.x;
    int lane = t & 15;
    int p = t >> 4;
    int node0 = blockIdx.x * 16;
    int node = node0 + p;
    const uint4* in4 = (const uint4*)in;
    float a[8];
#pragma unroll
    for (int j = 0; j < 8; ++j) a[j] = 0.f;
    uint4 sv = in4[(size_t)node * 16 + lane];
    acc8(a, sv, 1.f);
    int e0 = offs[node], e1 = offs[node + 1];
    int elast = e1 - 1;
    for (int e = e0; e < e1; e += 8) {
        int idx[8];
        float m[8];
#pragma unroll
        for (int i = 0; i < 8; ++i) {
            int ei = e + i;
            int ec = ei < elast ? ei : elast;
            idx[i] = csr[ec];
            m[i] = (ei < e1) ? 1.f : 0.f;
        }
        uint4 v[8];
#pragma unroll
        for (int i = 0; i < 8; ++i) v[i] = in4[(size_t)idx[i] * 16 + lane];
#pragma unroll
        for (int i = 0; i < 8; ++i) acc8(a, v[i], m[i]);
    }
    float4* row = (float4*)&sA[p][lane * 8];
    row[0] = make_float4(a[0], a[1], a[2], a[3]);
    row[1] = make_float4(a[4], a[5], a[6], a[7]);
    __syncthreads();
    if (t < DH) {
        float* pp = pp8 + (size_t)(blockIdx.x & 7) * NG * DH;
        int gprev = gidx[node0];
        float run = 0.f;
        for (int q = 0; q < 16; ++q) {
            int g = gidx[node0 + q];
            if (g != gprev) {
                atomicAdd(&pp[gprev * DH + t], run);
                run = 0.f;
                gprev = g;
            }
            run += sA[q][t];
        }
        atomicAdd(&pp[gprev * DH + t], run);
    }
}

// ---------------- dense matvec ----------------

__device__ __forceinline__ void fma4(float4& acc, float s, const float4& wv) {
    acc.x = fmaf(s, wv.x, acc.x);
    acc.y = fmaf(s, wv.y, acc.y);
    acc.z = fmaf(s, wv.z, acc.z);
    acc.w = fmaf(s, wv.w, acc.w);
}

__device__ __forceinline__ uint2 pack4h(const float4& a) {
    uint2 r;
    *(__half2*)&r.x = __floats2half2_rn(a.x, a.y);
    *(__half2*)&r.y = __floats2half2_rn(a.z, a.w);
    return r;
}

// x(fp32) @ W -> fp16 out (no bias/relu; agg epilogue applies them)
__global__ __launch_bounds__(256, 2) void k_mm_h(
    const float* __restrict__ A, const float* __restrict__ W,
    __half* __restrict__ out) {
    __shared__ __align__(16) float sW[DH * DH];     // 64 KB
    __shared__ __align__(16) float sA[32 * DH];     // 16 KB
    int t = threadIdx.x;
    int node0 = blockIdx.x * 32;
    {
        const float4* W4g = (const float4*)W;
        float4* sW4 = (float4*)sW;
        for (int i = t; i < DH * DH / 4; i += 256) sW4[i] = W4g[i];
        const float4* A4g = (const float4*)A + (size_t)node0 * 32;
        float4* sA4 = (float4*)sA;
        for (int i = t; i < 32 * DH / 4; i += 256) sA4[i] = A4g[i];
    }
    __syncthreads();

    int c4 = t & 31;
    int n0 = (t >> 5) * 4;
    const float4* sA4 = (const float4*)sA;
    const float4* sW4 = (const float4*)sW;
    float4 acc0, acc1, acc2, acc3;
    acc0.x = acc0.y = acc0.z = acc0.w = 0.f;
    acc1 = acc0; acc2 = acc0; acc3 = acc0;

#pragma unroll 2
    for (int kc = 0; kc < DH / 4; ++kc) {
        float4 a0 = sA4[(n0 + 0) * 32 + kc];
        float4 a1 = sA4[(n0 + 1) * 32 + kc];
        float4 a2 = sA4[(n0 + 2) * 32 + kc];
        float4 a3 = sA4[(n0 + 3) * 32 + kc];
        float4 w0 = sW4[(4 * kc + 0) * 32 + c4];
        float4 w1 = sW4[(4 * kc + 1) * 32 + c4];
        float4 w2 = sW4[(4 * kc + 2) * 32 + c4];
        float4 w3 = sW4[(4 * kc + 3) * 32 + c4];
        fma4(acc0, a0.x, w0); fma4(acc0, a0.y, w1); fma4(acc0, a0.z, w2); fma4(acc0, a0.w, w3);
        fma4(acc1, a1.x, w0); fma4(acc1, a1.y, w1); fma4(acc1, a1.z, w2); fma4(acc1, a1.w, w3);
        fma4(acc2, a2.x, w0); fma4(acc2, a2.y, w1); fma4(acc2, a2.z, w2); fma4(acc2, a2.w, w3);
        fma4(acc3, a3.x, w0); fma4(acc3, a3.y, w1); fma4(acc3, a3.z, w2); fma4(acc3, a3.w, w3);
    }

    uint2* out2 = (uint2*)out;   // 4 halfs per uint2, 32 per row
    out2[(size_t)(node0 + n0 + 0) * 32 + c4] = pack4h(acc0);
    out2[(size_t)(node0 + n0 + 1) * 32 + c4] = pack4h(acc1);
    out2[(size_t)(node0 + n0 + 2) * 32 + c4] = pack4h(acc2);
    out2[(size_t)(node0 + n0 + 3) * 32 + c4] = pack4h(acc3);
}

// ---------------- pooled = (sum of pp8 copies) @ W2 + cnt*b2 ----------------

__global__ __launch_bounds__(256, 2) void k_pool_mm(
    const float* __restrict__ pp8, const float* __restrict__ W,
    const float* __restrict__ bias, const int* __restrict__ cnt,
    float* __restrict__ pooled) {
    __shared__ __align__(16) float sW[DH * DH];
    __shared__ __align__(16) float sA[32 * DH];
    int t = threadIdx.x;
    int g0 = blockIdx.x * 32;
    {
        const float4* W4g = (const float4*)W;
        float4* sW4 = (float4*)sW;
        for (int i = t; i < DH * DH / 4; i += 256) sW4[i] = W4g[i];
        const float4* P4 = (const float4*)pp8;
        float4* sA4 = (float4*)sA;
        for (int i = t; i < 32 * DH / 4; i += 256) {
            float4 s;
            s.x = 0.f; s.y = 0.f; s.z = 0.f; s.w = 0.f;
#pragma unroll
            for (int c = 0; c < NSEG; ++c) {
                float4 v = P4[(size_t)c * NG * DH / 4 + (size_t)g0 * DH / 4 + i];
                s.x += v.x; s.y += v.y; s.z += v.z; s.w += v.w;
            }
            sA4[i] = s;
        }
    }
    __syncthreads();

    int c4 = t & 31;
    int n0 = (t >> 5) * 4;
    const float4* sA4 = (const float4*)sA;
    const float4* sW4 = (const float4*)sW;
    float4 acc0, acc1, acc2, acc3;
    acc0.x = acc0.y = acc0.z = acc0.w = 0.f;
    acc1 = acc0; acc2 = acc0; acc3 = acc0;

#pragma unroll 2
    for (int kc = 0; kc < DH / 4; ++kc) {
        float4 a0 = sA4[(n0 + 0) * 32 + kc];
        float4 a1 = sA4[(n0 + 1) * 32 + kc];
        float4 a2 = sA4[(n0 + 2) * 32 + kc];
        float4 a3 = sA4[(n0 + 3) * 32 + kc];
        float4 w0 = sW4[(4 * kc + 0) * 32 + c4];
        float4 w1 = sW4[(4 * kc + 1) * 32 + c4];
        float4 w2 = sW4[(4 * kc + 2) * 32 + c4];
        float4 w3 = sW4[(4 * kc + 3) * 32 + c4];
        fma4(acc0, a0.x, w0); fma4(acc0, a0.y, w1); fma4(acc0, a0.z, w2); fma4(acc0, a0.w, w3);
        fma4(acc1, a1.x, w0); fma4(acc1, a1.y, w1); fma4(acc1, a1.z, w2); fma4(acc1, a1.w, w3);
        fma4(acc2, a2.x, w0); fma4(acc2, a2.y, w1); fma4(acc2, a2.z, w2); fma4(acc2, a2.w, w3);
        fma4(acc3, a3.x, w0); fma4(acc3, a3.y, w1); fma4(acc3, a3.z, w2); fma4(acc3, a3.w, w3);
    }

    float4 b2v = ((const float4*)bias)[c4];
    float c0 = (float)cnt[g0 + n0 + 0];
    float c1 = (float)cnt[g0 + n0 + 1];
    float c2 = (float)cnt[g0 + n0 + 2];
    float c3 = (float)cnt[g0 + n0 + 3];
    fma4(acc0, c0, b2v);
    fma4(acc1, c1, b2v);
    fma4(acc2, c2, b2v);
    fma4(acc3, c3, b2v);

    float4* out4 = (float4*)pooled;
    out4[(size_t)(g0 + n0 + 0) * 32 + c4] = acc0;
    out4[(size_t)(g0 + n0 + 1) * 32 + c4] = acc1;
    out4[(size_t)(g0 + n0 + 2) * 32 + c4] = acc2;
    out4[(size_t)(g0 + n0 + 3) * 32 + c4] = acc3;
}

// ---------------- batchnorm stats ----------------

__global__ void k_bnstats(const float* __restrict__ pooled, float* __restrict__ mean,
                          float* __restrict__ rstd) {
    int c = blockIdx.x;
    int l = threadIdx.x;
    float s = 0.f, s2 = 0.f;
    for (int g = l; g < NG; g += 64) {
        float v = pooled[g * DH + c];
        s += v;
        s2 += v * v;
    }
#pragma unroll
    for (int off = 32; off > 0; off >>= 1) {
        s += __shfl_down(s, off, 64);
        s2 += __shfl_down(s2, off, 64);
    }
    if (l == 0) {
        float m = s * (1.f / NG);
        float var = s2 * (1.f / NG) - m * m;
        mean[c] = m;
        rstd[c] = rsqrtf(var + 1e-5f);
    }
}

// ---------------- BN + W3 + relu + W4 + log_softmax ----------------

__global__ __launch_bounds__(128) void k_tail(
    const float* __restrict__ pooled, const float* __restrict__ mean,
    const float* __restrict__ rstd, const float* __restrict__ gamma,
    const float* __restrict__ beta, const float* __restrict__ W3,
    const float* __restrict__ b3, const float* __restrict__ W4,
    const float* __restrict__ b4, float* __restrict__ out) {
    __shared__ __align__(16) float sW[DH * DH];
    __shared__ float sg[DH];
    __shared__ float sz[DH];
    __shared__ float slog[NC];
    __shared__ float slse;
    int g = blockIdx.x, t = threadIdx.x;
    {
        const float4* W34 = (const float4*)W3;
        float4* sW4 = (float4*)sW;
        for (int i = t; i < DH * DH / 4; i += 128) sW4[i] = W34[i];
    }
    float v = pooled[g * DH + t];
    v = (v - mean[t]) * rstd[t] * gamma[t] + beta[t];
    sg[t] = v;
    __syncthreads();
    float acc = b3[t];
#pragma unroll 4
    for (int k = 0; k < DH; ++k) acc = fmaf(sg[k], sW[k * DH + t], acc);
    sz[t] = fmaxf(acc, 0.f);
    __syncthreads();
    if (t < NC) {
        float a = b4[t];
        for (int k = 0; k < DH; ++k) a = fmaf(sz[k], W4[k * NC + t], a);
        slog[t] = a;
    }
    __syncthreads();
    if (t == 0) {
        float mx = slog[0];
        for (int j = 1; j < NC; ++j) mx = fmaxf(mx, slog[j]);
        float se = 0.f;
        for (int j = 0; j < NC; ++j) se += expf(slog[j] - mx);
        slse = mx + logf(se);
    }
    __syncthreads();
    if (t < NC) out[g * NC + t] = slog[t] - slse;
}

// ---------------- launch ----------------

extern "C" void kernel_launch(void* const* d_in, const int* in_sizes, int n_in,
                              void* d_out, int out_size, void* d_ws, size_t ws_size,
                              hipStream_t stream) {
    const float* x = (const float*)d_in[0];
    const int* ei = (const int*)d_in[1];
    const int* src = ei;            // edge_index[0]
    const int* dst = ei + NE;       // edge_index[1]
    const int* gidx = (const int*)d_in[2];
    const float* W1 = (const float*)d_in[3];
    const float* b1 = (const float*)d_in[4];
    const float* W2 = (const float*)d_in[5];
    const float* b2 = (const float*)d_in[6];
    const float* W3 = (const float*)d_in[7];
    const float* b3 = (const float*)d_in[8];
    const float* W4 = (const float*)d_in[9];
    const float* b4 = (const float*)d_in[10];
    const float* gamma = (const float*)d_in[11];
    const float* beta = (const float*)d_in[12];
    float* out = (float*)d_out;

    char* w = (char*)d_ws;
    auto take = [&](size_t bytes) {
        char* p = w;
        w += (bytes + 255) & ~size_t(255);
        return p;
    };
    int* counts = (int*)take((size_t)NN * 4);
    int* offsets = (int*)take((size_t)(NN + 1) * 4);
    int* cursor = (int*)take((size_t)NN * 4);
    int* bsum = (int*)take(512);
    int* csr = (int*)take((size_t)NE * 4);
    __half* y = (__half*)take((size_t)NN * DH * 2);    // x @ W1 (fp16)
    __half* z1 = (__half*)take((size_t)NN * DH * 2);   // relu(agg(y)+b1) (fp16)
    float* pp8 = (float*)take((size_t)NSEG * NG * DH * 4);   // XCD-private pool acc
    int* cnt = (int*)take((size_t)NG * 4);
    float* pooled = (float*)take((size_t)NG * DH * 4);
    float* meanb = (float*)take(DH * 4);
    float* rstdb = (float*)take(DH * 4);

    // CSR build (dst-indexed), XCD-partitioned atomics
    k_zero<<<(NSEG * NG * DH + 255) / 256, 256, 0, stream>>>(counts, pp8, cnt);
    k_hist_part<<<NCH * NSEG, 256, 0, stream>>>(dst, counts);
    k_scan_blocks<<<NB_SCAN, 256, 0, stream>>>(counts, offsets, bsum);
    k_scan_bsum<<<1, 128, 0, stream>>>(bsum);
    k_add_base<<<(NN + 255) / 256, 256, 0, stream>>>(offsets, bsum, cursor);
    k_fill_part<<<NCH * NSEG, 256, 0, stream>>>(src, dst, cursor, csr);
    k_cnt<<<NB_SCAN, 256, 0, stream>>>(gidx, cnt);

    // layer 1: y = x@W1 (fp16); z1 = relu(agg(y)+b1) (fp16)
    k_mm_h<<<NN / 32, 256, 0, stream>>>(x, W1, y);
    k_agg_h<<<NN / 16, 256, 0, stream>>>(y, offsets, csr, b1, z1);

    // layer 2: pooled_pre[g] = sum_{n in g} agg(z1)[n]; pooled = pre@W2 + cnt*b2
    k_agg_pool_h<<<NN / 16, 256, 0, stream>>>(z1, offsets, csr, gidx, pp8);
    k_pool_mm<<<NG / 32, 256, 0, stream>>>(pp8, W2, b2, cnt, pooled);

    k_bnstats<<<DH, 64, 0, stream>>>(pooled, meanb, rstdb);
    k_tail<<<NG, 128, 0, stream>>>(pooled, meanb, rstdb, gamma, beta, W3, b3, W4, b4, out);
}

// Round 6
// 470.602 us; speedup vs baseline: 1.6857x; 1.0966x over previous
//
#include <hip/hip_runtime.h>
#include <hip/hip_fp16.h>
#include <math.h>

#define NN 100000      // nodes
#define NE 1600000     // edges
#define DH 128         // feature dim
#define NG 512         // graphs
#define NC 10          // classes
#define NB_SCAN 98     // ceil(NN/1024)
#define NSEG 8         // XCD partitions for hist/fill
#define SEGN 12500     // nodes per segment
#define CHE 8192       // edges per chunk in partitioned hist/fill
#define NCH 196        // ceil(NE/CHE)
#define WPITCH 136     // fp16 LDS pitch for transposed W (16B-aligned, conflict-padded)

typedef __attribute__((ext_vector_type(8))) _Float16 f16x8;
typedef __attribute__((ext_vector_type(4))) float f32x4;

// ---------------- zero ----------------

__global__ void k_zero(int* __restrict__ counts, float* __restrict__ pp8,
                       int* __restrict__ cnt) {
    int i = blockIdx.x * 256 + threadIdx.x;
    if (i < NN) counts[i] = 0;
    if (i < NSEG * NG * DH) pp8[i] = 0.f;
    if (i < NG) cnt[i] = 0;
}

// ---------------- XCD-partitioned histogram over dst ----------------

__global__ __launch_bounds__(256) void k_hist_part(const int* __restrict__ dst,
                                                   int* __restrict__ counts) {
    int seg = blockIdx.x & 7;
    int chunk = blockIdx.x >> 3;
    int lo = seg * SEGN, hi = lo + SEGN;
    int e0 = chunk * CHE;
    int e1 = e0 + CHE < NE ? e0 + CHE : NE;
    for (int e = e0 + threadIdx.x; e < e1; e += 256) {
        int d = dst[e];
        if (d >= lo && d < hi) atomicAdd(&counts[d], 1);
    }
}

__global__ void k_scan_blocks(const int* __restrict__ counts, int* __restrict__ offsets,
                              int* __restrict__ bsum) {
    __shared__ int sd[256];
    int t = threadIdx.x;
    int base = blockIdx.x * 1024 + t * 4;
    int v0 = (base + 0 < NN) ? counts[base + 0] : 0;
    int v1 = (base + 1 < NN) ? counts[base + 1] : 0;
    int v2 = (base + 2 < NN) ? counts[base + 2] : 0;
    int v3 = (base + 3 < NN) ? counts[base + 3] : 0;
    int s = v0 + v1 + v2 + v3;
    sd[t] = s;
    __syncthreads();
    for (int off = 1; off < 256; off <<= 1) {
        int x = (t >= off) ? sd[t - off] : 0;
        __syncthreads();
        sd[t] += x;
        __syncthreads();
    }
    int run = sd[t] - s;
    if (base + 0 < NN) offsets[base + 0] = run; run += v0;
    if (base + 1 < NN) offsets[base + 1] = run; run += v1;
    if (base + 2 < NN) offsets[base + 2] = run; run += v2;
    if (base + 3 < NN) offsets[base + 3] = run; run += v3;
    if (t == 255) bsum[blockIdx.x] = run;
}

__global__ void k_scan_bsum(int* __restrict__ bsum) {
    __shared__ int sd[128];
    int t = threadIdx.x;
    int v = (t < NB_SCAN) ? bsum[t] : 0;
    sd[t] = v;
    __syncthreads();
    for (int off = 1; off < 128; off <<= 1) {
        int x = (t >= off) ? sd[t - off] : 0;
        __syncthreads();
        sd[t] += x;
        __syncthreads();
    }
    if (t < NB_SCAN) bsum[t] = sd[t] - v;
}

__global__ void k_add_base(int* __restrict__ offsets, const int* __restrict__ bsum,
                           int* __restrict__ cursor) {
    int i = blockIdx.x * 256 + threadIdx.x;
    if (i < NN) {
        int o = offsets[i] + bsum[i >> 10];
        offsets[i] = o;
        cursor[i] = o;
    }
    if (i == 0) offsets[NN] = NE;
}

__global__ __launch_bounds__(256) void k_fill_part(const int* __restrict__ src,
                                                   const int* __restrict__ dst,
                                                   int* __restrict__ cursor,
                                                   int* __restrict__ csr) {
    int seg = blockIdx.x & 7;
    int chunk = blockIdx.x >> 3;
    int lo = seg * SEGN, hi = lo + SEGN;
    int e0 = chunk * CHE;
    int e1 = e0 + CHE < NE ? e0 + CHE : NE;
    for (int e = e0 + threadIdx.x; e < e1; e += 256) {
        int d = dst[e];
        if (d >= lo && d < hi) {
            int p = atomicAdd(&cursor[d], 1);
            csr[p] = src[e];
        }
    }
}

// ---------------- per-graph node counts (idx is sorted -> run-length) --------

__global__ void k_cnt(const int* __restrict__ gidx, int* __restrict__ cnt) {
    int t = threadIdx.x;
    int n0 = blockIdx.x * 1024 + t * 4;
    if (n0 >= NN) return;
    int g = gidx[n0];
    int run = 1;
    for (int j = 1; j < 4; ++j) {
        int n = n0 + j;
        if (n < NN) {
            int gg = gidx[n];
            if (gg == g) {
                run++;
            } else {
                atomicAdd(&cnt[g], run);
                g = gg;
                run = 1;
            }
        }
    }
    atomicAdd(&cnt[g], run);
}

// ---------------- fp16 helpers ----------------

__device__ __forceinline__ void acc8(float* a, const uint4& v, float m) {
    float2 f;
    f = __half22float2(*(const __half2*)&v.x); a[0] = fmaf(m, f.x, a[0]); a[1] = fmaf(m, f.y, a[1]);
    f = __half22float2(*(const __half2*)&v.y); a[2] = fmaf(m, f.x, a[2]); a[3] = fmaf(m, f.y, a[3]);
    f = __half22float2(*(const __half2*)&v.z); a[4] = fmaf(m, f.x, a[4]); a[5] = fmaf(m, f.y, a[5]);
    f = __half22float2(*(const __half2*)&v.w); a[6] = fmaf(m, f.x, a[6]); a[7] = fmaf(m, f.y, a[7]);
}

// ---------------- gather (fp16 rows) + bias + relu -> fp16 out --------------

__global__ __launch_bounds__(256, 6) void k_agg_h(
    const __half* __restrict__ in, const int* __restrict__ offs,
    const int* __restrict__ csr, const float* __restrict__ bias,
    __half* __restrict__ outA) {
    int t = threadIdx.x;
    int lane = t & 15;
    int node = blockIdx.x * 16 + (t >> 4);
    const uint4* in4 = (const uint4*)in;   // 16 uint4 per row
    float a[8];
#pragma unroll
    for (int j = 0; j < 8; ++j) a[j] = 0.f;
    uint4 sv = in4[(size_t)node * 16 + lane];
    acc8(a, sv, 1.f);                      // self loop
    int e0 = offs[node], e1 = offs[node + 1];
    int elast = e1 - 1;
    for (int e = e0; e < e1; e += 8) {
        int idx[8];
        float m[8];
#pragma unroll
        for (int i = 0; i < 8; ++i) {
            int ei = e + i;
            int ec = ei < elast ? ei : elast;   // clamp: masked slots re-read hot row
            idx[i] = csr[ec];
            m[i] = (ei < e1) ? 1.f : 0.f;
        }
        uint4 v[8];
#pragma unroll
        for (int i = 0; i < 8; ++i) v[i] = in4[(size_t)idx[i] * 16 + lane];
#pragma unroll
        for (int i = 0; i < 8; ++i) acc8(a, v[i], m[i]);
    }
    float4 b0 = ((const float4*)bias)[lane * 2];
    float4 b1v = ((const float4*)bias)[lane * 2 + 1];
    a[0] = fmaxf(a[0] + b0.x, 0.f);  a[1] = fmaxf(a[1] + b0.y, 0.f);
    a[2] = fmaxf(a[2] + b0.z, 0.f);  a[3] = fmaxf(a[3] + b0.w, 0.f);
    a[4] = fmaxf(a[4] + b1v.x, 0.f); a[5] = fmaxf(a[5] + b1v.y, 0.f);
    a[6] = fmaxf(a[6] + b1v.z, 0.f); a[7] = fmaxf(a[7] + b1v.w, 0.f);
    uint4 o;
    *(__half2*)&o.x = __floats2half2_rn(a[0], a[1]);
    *(__half2*)&o.y = __floats2half2_rn(a[2], a[3]);
    *(__half2*)&o.z = __floats2half2_rn(a[4], a[5]);
    *(__half2*)&o.w = __floats2half2_rn(a[6], a[7]);
    ((uint4*)outA)[(size_t)node * 16 + lane] = o;
}

// ---------------- gather (fp16 rows) + per-graph pooling --------------------

__global__ __launch_bounds__(256, 6) void k_agg_pool_h(
    const __half* __restrict__ in, const int* __restrict__ offs,
    const int* __restrict__ csr, const int* __restrict__ gidx,
    float* __restrict__ pp8) {
    __shared__ __align__(16) float sA[16][DH];
    int t = threadIdx.x;
    int lane = t & 15;
    int p = t >> 4;
    int node0 = blockIdx.x * 16;
    int node = node0 + p;
    const uint4* in4 = (const uint4*)in;
    float a[8];
#pragma unroll
    for (int j = 0; j < 8; ++j) a[j] = 0.f;
    uint4 sv = in4[(size_t)node * 16 + lane];
    acc8(a, sv, 1.f);
    int e0 = offs[node], e1 = offs[node + 1];
    int elast = e1 - 1;
    for (int e = e0; e < e1; e += 8) {
        int idx[8];
        float m[8];
#pragma unroll
        for (int i = 0; i < 8; ++i) {
            int ei = e + i;
            int ec = ei < elast ? ei : elast;
            idx[i] = csr[ec];
            m[i] = (ei < e1) ? 1.f : 0.f;
        }
        uint4 v[8];
#pragma unroll
        for (int i = 0; i < 8; ++i) v[i] = in4[(size_t)idx[i] * 16 + lane];
#pragma unroll
        for (int i = 0; i < 8; ++i) acc8(a, v[i], m[i]);
    }
    float4* row = (float4*)&sA[p][lane * 8];
    row[0] = make_float4(a[0], a[1], a[2], a[3]);
    row[1] = make_float4(a[4], a[5], a[6], a[7]);
    __syncthreads();
    if (t < DH) {
        float* pp = pp8 + (size_t)(blockIdx.x & 7) * NG * DH;
        int gprev = gidx[node0];
        float run = 0.f;
        for (int q = 0; q < 16; ++q) {
            int g = gidx[node0 + q];
            if (g != gprev) {
                atomicAdd(&pp[gprev * DH + t], run);
                run = 0.f;
                gprev = g;
            }
            run += sA[q][t];
        }
        atomicAdd(&pp[gprev * DH + t], run);
    }
}

// ---------------- MFMA GEMM: y = x(fp32->fp16) @ W1 -> fp16 ----------------
// 4 waves/block, 16 nodes/wave. W transposed in LDS (fp16, padded pitch).
// Per wave: 8 col-tiles x 4 k-tiles of v_mfma_f32_16x16x32_f16.
// A-frag: lane holds A[m=lane&15][k=quad*8+j]; B-frag: B[k=quad*8+j][n=lane&15];
// C/D: col=lane&15, row=quad*4+reg (verified layouts).

__global__ __launch_bounds__(256, 3) void k_mm_mfma(
    const float* __restrict__ A, const float* __restrict__ W,
    __half* __restrict__ out) {
    __shared__ _Float16 sWT[DH * WPITCH];          // W^T, [n][k], ~34 KB
    __shared__ __align__(16) _Float16 sOut[4][16][DH];  // 16 KB store staging
    int t = threadIdx.x;
    int wv = t >> 6;
    int lane = t & 63;
    // stage W transposed as fp16 (coalesced global read)
    for (int i = t; i < DH * DH; i += 256) {
        int k = i >> 7, n = i & 127;
        sWT[n * WPITCH + k] = (_Float16)W[i];
    }
    __syncthreads();

    int m = lane & 15;
    int quad = lane >> 4;
    int node0 = blockIdx.x * 64 + wv * 16;
    int nodeA = node0 + m;
    if (nodeA >= NN) nodeA = NN - 1;
    const float* arow = A + (size_t)nodeA * DH;

    f16x8 afrag[4];
#pragma unroll
    for (int kt = 0; kt < 4; ++kt) {
        int k0 = kt * 32 + quad * 8;
        float4 u0 = *(const float4*)(arow + k0);
        float4 u1 = *(const float4*)(arow + k0 + 4);
        afrag[kt][0] = (_Float16)u0.x; afrag[kt][1] = (_Float16)u0.y;
        afrag[kt][2] = (_Float16)u0.z; afrag[kt][3] = (_Float16)u0.w;
        afrag[kt][4] = (_Float16)u1.x; afrag[kt][5] = (_Float16)u1.y;
        afrag[kt][6] = (_Float16)u1.z; afrag[kt][7] = (_Float16)u1.w;
    }

#pragma unroll
    for (int ct = 0; ct < 8; ++ct) {
        f32x4 acc = {0.f, 0.f, 0.f, 0.f};
        int n = ct * 16 + m;
#pragma unroll
        for (int kt = 0; kt < 4; ++kt) {
            int k0 = kt * 32 + quad * 8;
            f16x8 b = *(const f16x8*)&sWT[n * WPITCH + k0];
            acc = __builtin_amdgcn_mfma_f32_16x16x32_f16(afrag[kt], b, acc, 0, 0, 0);
        }
#pragma unroll
        for (int r = 0; r < 4; ++r)
            sOut[wv][quad * 4 + r][ct * 16 + m] = (_Float16)acc[r];
    }
    __syncthreads();

    // coalesced fp16 store: wave wv writes its 16 rows x 128 ch (4 KB)
    const uint4* so = (const uint4*)&sOut[wv][0][0];
    for (int i = lane; i < 256; i += 64) {
        int row = i >> 4;
        int node = node0 + row;
        if (node < NN) ((uint4*)out)[(size_t)node * 16 + (i & 15)] = so[i];
    }
}

// ---------------- dense matvec helpers ----------------

__device__ __forceinline__ void fma4(float4& acc, float s, const float4& wv) {
    acc.x = fmaf(s, wv.x, acc.x);
    acc.y = fmaf(s, wv.y, acc.y);
    acc.z = fmaf(s, wv.z, acc.z);
    acc.w = fmaf(s, wv.w, acc.w);
}

// ---------------- pooled = (sum of pp8 copies) @ W2 + cnt*b2 ----------------

__global__ __launch_bounds__(256, 2) void k_pool_mm(
    const float* __restrict__ pp8, const float* __restrict__ W,
    const float* __restrict__ bias, const int* __restrict__ cnt,
    float* __restrict__ pooled) {
    __shared__ __align__(16) float sW[DH * DH];
    __shared__ __align__(16) float sA[32 * DH];
    int t = threadIdx.x;
    int g0 = blockIdx.x * 32;
    {
        const float4* W4g = (const float4*)W;
        float4* sW4 = (float4*)sW;
        for (int i = t; i < DH * DH / 4; i += 256) sW4[i] = W4g[i];
        const float4* P4 = (const float4*)pp8;
        float4* sA4 = (float4*)sA;
        for (int i = t; i < 32 * DH / 4; i += 256) {
            float4 s;
            s.x = 0.f; s.y = 0.f; s.z = 0.f; s.w = 0.f;
#pragma unroll
            for (int c = 0; c < NSEG; ++c) {
                float4 v = P4[(size_t)c * NG * DH / 4 + (size_t)g0 * DH / 4 + i];
                s.x += v.x; s.y += v.y; s.z += v.z; s.w += v.w;
            }
            sA4[i] = s;
        }
    }
    __syncthreads();

    int c4 = t & 31;
    int n0 = (t >> 5) * 4;
    const float4* sA4 = (const float4*)sA;
    const float4* sW4 = (const float4*)sW;
    float4 acc0, acc1, acc2, acc3;
    acc0.x = acc0.y = acc0.z = acc0.w = 0.f;
    acc1 = acc0; acc2 = acc0; acc3 = acc0;

#pragma unroll 2
    for (int kc = 0; kc < DH / 4; ++kc) {
        float4 a0 = sA4[(n0 + 0) * 32 + kc];
        float4 a1 = sA4[(n0 + 1) * 32 + kc];
        float4 a2 = sA4[(n0 + 2) * 32 + kc];
        float4 a3 = sA4[(n0 + 3) * 32 + kc];
        float4 w0 = sW4[(4 * kc + 0) * 32 + c4];
        float4 w1 = sW4[(4 * kc + 1) * 32 + c4];
        float4 w2 = sW4[(4 * kc + 2) * 32 + c4];
        float4 w3 = sW4[(4 * kc + 3) * 32 + c4];
        fma4(acc0, a0.x, w0); fma4(acc0, a0.y, w1); fma4(acc0, a0.z, w2); fma4(acc0, a0.w, w3);
        fma4(acc1, a1.x, w0); fma4(acc1, a1.y, w1); fma4(acc1, a1.z, w2); fma4(acc1, a1.w, w3);
        fma4(acc2, a2.x, w0); fma4(acc2, a2.y, w1); fma4(acc2, a2.z, w2); fma4(acc2, a2.w, w3);
        fma4(acc3, a3.x, w0); fma4(acc3, a3.y, w1); fma4(acc3, a3.z, w2); fma4(acc3, a3.w, w3);
    }

    float4 b2v = ((const float4*)bias)[c4];
    float c0 = (float)cnt[g0 + n0 + 0];
    float c1 = (float)cnt[g0 + n0 + 1];
    float c2 = (float)cnt[g0 + n0 + 2];
    float c3 = (float)cnt[g0 + n0 + 3];
    fma4(acc0, c0, b2v);
    fma4(acc1, c1, b2v);
    fma4(acc2, c2, b2v);
    fma4(acc3, c3, b2v);

    float4* out4 = (float4*)pooled;
    out4[(size_t)(g0 + n0 + 0) * 32 + c4] = acc0;
    out4[(size_t)(g0 + n0 + 1) * 32 + c4] = acc1;
    out4[(size_t)(g0 + n0 + 2) * 32 + c4] = acc2;
    out4[(size_t)(g0 + n0 + 3) * 32 + c4] = acc3;
}

// ---------------- batchnorm stats ----------------

__global__ void k_bnstats(const float* __restrict__ pooled, float* __restrict__ mean,
                          float* __restrict__ rstd) {
    int c = blockIdx.x;
    int l = threadIdx.x;
    float s = 0.f, s2 = 0.f;
    for (int g = l; g < NG; g += 64) {
        float v = pooled[g * DH + c];
        s += v;
        s2 += v * v;
    }
#pragma unroll
    for (int off = 32; off > 0; off >>= 1) {
        s += __shfl_down(s, off, 64);
        s2 += __shfl_down(s2, off, 64);
    }
    if (l == 0) {
        float m = s * (1.f / NG);
        float var = s2 * (1.f / NG) - m * m;
        mean[c] = m;
        rstd[c] = rsqrtf(var + 1e-5f);
    }
}

// ---------------- BN + W3 + relu + W4 + log_softmax ----------------

__global__ __launch_bounds__(128) void k_tail(
    const float* __restrict__ pooled, const float* __restrict__ mean,
    const float* __restrict__ rstd, const float* __restrict__ gamma,
    const float* __restrict__ beta, const float* __restrict__ W3,
    const float* __restrict__ b3, const float* __restrict__ W4,
    const float* __restrict__ b4, float* __restrict__ out) {
    __shared__ __align__(16) float sW[DH * DH];
    __shared__ float sg[DH];
    __shared__ float sz[DH];
    __shared__ float slog[NC];
    __shared__ float slse;
    int g = blockIdx.x, t = threadIdx.x;
    {
        const float4* W34 = (const float4*)W3;
        float4* sW4 = (float4*)sW;
        for (int i = t; i < DH * DH / 4; i += 128) sW4[i] = W34[i];
    }
    float v = pooled[g * DH + t];
    v = (v - mean[t]) * rstd[t] * gamma[t] + beta[t];
    sg[t] = v;
    __syncthreads();
    float acc = b3[t];
#pragma unroll 4
    for (int k = 0; k < DH; ++k) acc = fmaf(sg[k], sW[k * DH + t], acc);
    sz[t] = fmaxf(acc, 0.f);
    __syncthreads();
    if (t < NC) {
        float a = b4[t];
        for (int k = 0; k < DH; ++k) a = fmaf(sz[k], W4[k * NC + t], a);
        slog[t] = a;
    }
    __syncthreads();
    if (t == 0) {
        float mx = slog[0];
        for (int j = 1; j < NC; ++j) mx = fmaxf(mx, slog[j]);
        float se = 0.f;
        for (int j = 0; j < NC; ++j) se += expf(slog[j] - mx);
        slse = mx + logf(se);
    }
    __syncthreads();
    if (t < NC) out[g * NC + t] = slog[t] - slse;
}

// ---------------- launch ----------------

extern "C" void kernel_launch(void* const* d_in, const int* in_sizes, int n_in,
                              void* d_out, int out_size, void* d_ws, size_t ws_size,
                              hipStream_t stream) {
    const float* x = (const float*)d_in[0];
    const int* ei = (const int*)d_in[1];
    const int* src = ei;            // edge_index[0]
    const int* dst = ei + NE;       // edge_index[1]
    const int* gidx = (const int*)d_in[2];
    const float* W1 = (const float*)d_in[3];
    const float* b1 = (const float*)d_in[4];
    const float* W2 = (const float*)d_in[5];
    const float* b2 = (const float*)d_in[6];
    const float* W3 = (const float*)d_in[7];
    const float* b3 = (const float*)d_in[8];
    const float* W4 = (const float*)d_in[9];
    const float* b4 = (const float*)d_in[10];
    const float* gamma = (const float*)d_in[11];
    const float* beta = (const float*)d_in[12];
    float* out = (float*)d_out;

    char* w = (char*)d_ws;
    auto take = [&](size_t bytes) {
        char* p = w;
        w += (bytes + 255) & ~size_t(255);
        return p;
    };
    int* counts = (int*)take((size_t)NN * 4);
    int* offsets = (int*)take((size_t)(NN + 1) * 4);
    int* cursor = (int*)take((size_t)NN * 4);
    int* bsum = (int*)take(512);
    int* csr = (int*)take((size_t)NE * 4);
    __half* y = (__half*)take((size_t)NN * DH * 2);    // x @ W1 (fp16)
    __half* z1 = (__half*)take((size_t)NN * DH * 2);   // relu(agg(y)+b1) (fp16)
    float* pp8 = (float*)take((size_t)NSEG * NG * DH * 4);   // XCD-private pool acc
    int* cnt = (int*)take((size_t)NG * 4);
    float* pooled = (float*)take((size_t)NG * DH * 4);
    float* meanb = (float*)take(DH * 4);
    float* rstdb = (float*)take(DH * 4);

    // CSR build (dst-indexed), XCD-partitioned atomics
    k_zero<<<(NSEG * NG * DH + 255) / 256, 256, 0, stream>>>(counts, pp8, cnt);
    k_hist_part<<<NCH * NSEG, 256, 0, stream>>>(dst, counts);
    k_scan_blocks<<<NB_SCAN, 256, 0, stream>>>(counts, offsets, bsum);
    k_scan_bsum<<<1, 128, 0, stream>>>(bsum);
    k_add_base<<<(NN + 255) / 256, 256, 0, stream>>>(offsets, bsum, cursor);
    k_fill_part<<<NCH * NSEG, 256, 0, stream>>>(src, dst, cursor, csr);
    k_cnt<<<NB_SCAN, 256, 0, stream>>>(gidx, cnt);

    // layer 1: y = x@W1 via MFMA (fp16); z1 = relu(agg(y)+b1) (fp16)
    k_mm_mfma<<<(NN + 63) / 64, 256, 0, stream>>>(x, W1, y);
    k_agg_h<<<NN / 16, 256, 0, stream>>>(y, offsets, csr, b1, z1);

    // layer 2: pooled_pre[g] = sum_{n in g} agg(z1)[n]; pooled = pre@W2 + cnt*b2
    k_agg_pool_h<<<NN / 16, 256, 0, stream>>>(z1, offsets, csr, gidx, pp8);
    k_pool_mm<<<NG / 32, 256, 0, stream>>>(pp8, W2, b2, cnt, pooled);

    k_bnstats<<<DH, 64, 0, stream>>>(pooled, meanb, rstdb);
    k_tail<<<NG, 128, 0, stream>>>(pooled, meanb, rstdb, gamma, beta, W3, b3, W4, b4, out);
}